// Round 1
// baseline (774.168 us; speedup 1.0000x reference)
//
#include <hip/hip_runtime.h>
#include <cstddef>

// Problem constants (hard-coded from reference):
// D=256, NH=8, NL=4, NP=4, DH=32, B=4, LV=5440, DFF=1024
// SHAPES = {64,64},{32,32},{16,16},{8,8}; level_start = {0,4096,5120,5376}
#define DMODEL 256
#define NHEAD  8
#define NLVL   4
#define NPTS   4
#define DHEAD  32
#define BATCH  4
#define LVTOT  5440
#define DFF    1024
#define MROWS  (BATCH * LVTOT)   // 21760, divisible by 64 (21760 = 64*340)

// ---------------------------------------------------------------------------
// Generic fp32 tiled GEMM: C[M,N] = A[M,K] @ W[K,N] + bias[N], optional ReLU.
// Requires M%64==0, N%64==0, K%16==0.
// 64x64 output tile per 256-thread block, 4x4 per thread, K staged in 16-chunks.
// ---------------------------------------------------------------------------
__global__ __launch_bounds__(256) void gemm_f32(
    const float* __restrict__ A, const float* __restrict__ W,
    const float* __restrict__ bias, float* __restrict__ C,
    int M, int N, int K, int relu)
{
    __shared__ float As[16][68];   // [k][m], pad to 68 (16B-aligned rows, low conflict)
    __shared__ float Bs[16][68];   // [k][n]

    const int tid = threadIdx.x;
    const int tx = tid & 15;       // col quad 0..15
    const int ty = tid >> 4;       // row quad 0..15
    const int mtiles = M >> 6;
    const int bm = blockIdx.x % mtiles;
    const int bn = blockIdx.x / mtiles;
    const int row0 = bm << 6;
    const int col0 = bn << 6;

    float c[4][4] = {};

    const int ka = tid & 15;       // A-load k
    const int ma = tid >> 4;       // A-load m base
    const int nb = tid & 63;       // W-load n
    const int kb = tid >> 6;       // W-load k base (0..3)

    for (int k0 = 0; k0 < K; k0 += 16) {
        #pragma unroll
        for (int i = 0; i < 4; ++i) {
            int m = ma + i * 16;
            As[ka][m] = A[(size_t)(row0 + m) * K + k0 + ka];
        }
        #pragma unroll
        for (int i = 0; i < 4; ++i) {
            int k = kb + i * 4;
            Bs[k][nb] = W[(size_t)(k0 + k) * N + col0 + nb];
        }
        __syncthreads();

        #pragma unroll
        for (int kk = 0; kk < 16; ++kk) {
            float a[4], b[4];
            #pragma unroll
            for (int i = 0; i < 4; ++i) a[i] = As[kk][(ty << 2) + i];
            #pragma unroll
            for (int j = 0; j < 4; ++j) b[j] = Bs[kk][(tx << 2) + j];
            #pragma unroll
            for (int i = 0; i < 4; ++i)
                #pragma unroll
                for (int j = 0; j < 4; ++j)
                    c[i][j] += a[i] * b[j];
        }
        __syncthreads();
    }

    // epilogue: bias (+relu), vectorized store
    #pragma unroll
    for (int i = 0; i < 4; ++i) {
        int r = row0 + (ty << 2) + i;
        float4 o;
        float b0 = bias[col0 + (tx << 2) + 0];
        float b1 = bias[col0 + (tx << 2) + 1];
        float b2 = bias[col0 + (tx << 2) + 2];
        float b3 = bias[col0 + (tx << 2) + 3];
        o.x = c[i][0] + b0; o.y = c[i][1] + b1;
        o.z = c[i][2] + b2; o.w = c[i][3] + b3;
        if (relu) {
            o.x = fmaxf(o.x, 0.f); o.y = fmaxf(o.y, 0.f);
            o.z = fmaxf(o.z, 0.f); o.w = fmaxf(o.w, 0.f);
        }
        *reinterpret_cast<float4*>(&C[(size_t)r * N + col0 + (tx << 2)]) = o;
    }
}

// ---------------------------------------------------------------------------
// Softmax over groups of 16 within each row of 128 (in-place).
// attn layout: [MROWS][128], col = h*16 + (l*4+p); softmax over the 16.
// ---------------------------------------------------------------------------
__global__ __launch_bounds__(128) void softmax16(float* __restrict__ attn)
{
    const size_t row = blockIdx.x;
    const int t = threadIdx.x;                 // h*16 + i, groups aligned in wave
    float v = attn[row * 128 + t];
    float m = v;
    #pragma unroll
    for (int s = 1; s < 16; s <<= 1) m = fmaxf(m, __shfl_xor(m, s));
    float e = expf(v - m);
    float sum = e;
    #pragma unroll
    for (int s = 1; s < 16; s <<= 1) sum += __shfl_xor(sum, s);
    attn[row * 128 + t] = e / sum;
}

// ---------------------------------------------------------------------------
// Deformable sampling.
// vproj: [B][LV][256] (col = h*32+d), off: [MROWS][256] (col = h*32+l*8+p*2+c),
// attn(probs): [MROWS][128], refs: [MROWS][4][2], out(msda): [MROWS][256].
// 32 lanes per (b,q,h) unit (lane = d), 8 units per 256-thread block.
// ---------------------------------------------------------------------------
__global__ __launch_bounds__(256) void msda_sample(
    const float* __restrict__ vproj, const float* __restrict__ off,
    const float* __restrict__ attn, const float* __restrict__ refs,
    float* __restrict__ out)
{
    const int lane = threadIdx.x & 31;                 // d within head
    const int unit = (blockIdx.x << 3) + (threadIdx.x >> 5);
    const int h  = unit & 7;
    const int bq = unit >> 3;                          // b*LV + q
    const int b  = bq / LVTOT;

    const int   lvlH[4] = {64, 32, 16, 8};
    const int   lvlW[4] = {64, 32, 16, 8};
    const int   lsi[4]  = {0, 4096, 5120, 5376};

    const float* offrow = off  + (size_t)bq * 256 + h * 32;
    const float* arow   = attn + (size_t)bq * 128 + h * 16;
    const float* rrow   = refs + (size_t)bq * 8;
    const float* vb     = vproj + (size_t)b * LVTOT * 256 + h * 32 + lane;

    float acc = 0.f;
    #pragma unroll
    for (int l = 0; l < 4; ++l) {
        const int   Wi = lvlW[l], Hi = lvlH[l];
        const float Wf = (float)Wi, Hf = (float)Hi;
        const float rx = rrow[l * 2 + 0];
        const float ry = rrow[l * 2 + 1];
        const float* vlev = vb + (size_t)lsi[l] * 256;
        #pragma unroll
        for (int p = 0; p < 4; ++p) {
            const float ox = offrow[l * 8 + p * 2 + 0];
            const float oy = offrow[l * 8 + p * 2 + 1];
            const float aw = arow[l * 4 + p];
            const float x = rx * Wf + ox - 0.5f;
            const float y = ry * Hf + oy - 0.5f;
            const float x0 = floorf(x), y0 = floorf(y);
            const float tx = x - x0, ty = y - y0;
            const int xi = (int)x0, yi = (int)y0;
            const float w00 = (1.f - tx) * (1.f - ty);
            const float w10 = tx * (1.f - ty);
            const float w01 = (1.f - tx) * ty;
            const float w11 = tx * ty;
            float s = 0.f;
            const bool xin0 = (xi >= 0) && (xi < Wi);
            const bool xin1 = (xi + 1 >= 0) && (xi + 1 < Wi);
            const bool yin0 = (yi >= 0) && (yi < Hi);
            const bool yin1 = (yi + 1 >= 0) && (yi + 1 < Hi);
            if (xin0 && yin0) s += w00 * vlev[(size_t)(yi * Wi + xi) * 256];
            if (xin1 && yin0) s += w10 * vlev[(size_t)(yi * Wi + xi + 1) * 256];
            if (xin0 && yin1) s += w01 * vlev[(size_t)((yi + 1) * Wi + xi) * 256];
            if (xin1 && yin1) s += w11 * vlev[(size_t)((yi + 1) * Wi + xi + 1) * 256];
            acc += aw * s;
        }
    }
    out[(size_t)bq * 256 + h * 32 + lane] = acc;
}

// ---------------------------------------------------------------------------
// LayerNorm over 256, fused adds.
//   x = x1 + (x2? x2 : 0);  y = LN(x)*g + b;  out = (res? res : 0) + y
// One wave per row, 4 rows per 256-thread block.
// ---------------------------------------------------------------------------
__global__ __launch_bounds__(256) void ln_fused(
    const float* __restrict__ x1, const float* __restrict__ x2,
    const float* __restrict__ res,
    const float* __restrict__ g, const float* __restrict__ bta,
    float* __restrict__ out)
{
    const int row  = (blockIdx.x << 2) + (threadIdx.x >> 6);
    const int lane = threadIdx.x & 63;
    const size_t base = (size_t)row * 256 + lane * 4;

    float4 v = *reinterpret_cast<const float4*>(&x1[base]);
    if (x2) {
        float4 u = *reinterpret_cast<const float4*>(&x2[base]);
        v.x += u.x; v.y += u.y; v.z += u.z; v.w += u.w;
    }
    float s1 = v.x + v.y + v.z + v.w;
    float s2 = v.x * v.x + v.y * v.y + v.z * v.z + v.w * v.w;
    #pragma unroll
    for (int s = 1; s < 64; s <<= 1) {
        s1 += __shfl_xor(s1, s);
        s2 += __shfl_xor(s2, s);
    }
    const float mu  = s1 * (1.f / 256.f);
    const float var = s2 * (1.f / 256.f) - mu * mu;
    const float rstd = rsqrtf(var + 1e-5f);

    float4 gg = *reinterpret_cast<const float4*>(&g[lane * 4]);
    float4 bb = *reinterpret_cast<const float4*>(&bta[lane * 4]);
    float4 o;
    o.x = (v.x - mu) * rstd * gg.x + bb.x;
    o.y = (v.y - mu) * rstd * gg.y + bb.y;
    o.z = (v.z - mu) * rstd * gg.z + bb.z;
    o.w = (v.w - mu) * rstd * gg.w + bb.w;
    if (res) {
        float4 r = *reinterpret_cast<const float4*>(&res[base]);
        o.x += r.x; o.y += r.y; o.z += r.z; o.w += r.w;
    }
    *reinterpret_cast<float4*>(&out[base]) = o;
}

// ---------------------------------------------------------------------------
extern "C" void kernel_launch(void* const* d_in, const int* in_sizes, int n_in,
                              void* d_out, int out_size, void* d_ws, size_t ws_size,
                              hipStream_t stream)
{
    const float* query  = (const float*)d_in[0];
    const float* refs   = (const float*)d_in[1];
    const float* value  = (const float*)d_in[2];
    // d_in[3]=spatial_shapes(int32), d_in[4]=level_start_index(int32): hard-coded
    const float* W_off  = (const float*)d_in[5];
    const float* b_off  = (const float*)d_in[6];
    const float* W_attn = (const float*)d_in[7];
    const float* b_attn = (const float*)d_in[8];
    const float* W_val  = (const float*)d_in[9];
    const float* b_val  = (const float*)d_in[10];
    const float* W_out  = (const float*)d_in[11];
    const float* b_out  = (const float*)d_in[12];
    const float* ln1g   = (const float*)d_in[13];
    const float* ln1b   = (const float*)d_in[14];
    const float* ln2g   = (const float*)d_in[15];
    const float* ln2b   = (const float*)d_in[16];
    const float* W_ff1  = (const float*)d_in[17];
    const float* b_ff1  = (const float*)d_in[18];
    const float* W_ff2  = (const float*)d_in[19];
    const float* b_ff2  = (const float*)d_in[20];
    float* out = (float*)d_out;
    float* ws  = (float*)d_ws;

    const size_t R = (size_t)MROWS * 256;   // 5,570,560 floats
    // Workspace layout (total 6R floats = ~134 MB), with lifetime-based reuse:
    float* qbuf  = ws;            // [0,  R): q = value + LN(msda proj), lives to end
    float* tmp   = ws + R;        // [R, 2R): out-proj result; later reused as f2
    float* vproj = ws + 2 * R;    // [2R,3R): value projection (dead after sampling)
    float* offb  = ws + 3 * R;    // [3R,4R): offsets (dead after sampling)
    float* attnb = ws + 4 * R;    // [4R,4.5R): attn logits->probs (dead after sampling)
    float* msda  = ws + 4 * R + R / 2;  // [4.5R,5.5R): sampled output (dead after out-proj)
    float* f1    = ws + 2 * R;    // [2R,6R): FF1 output (overlaps dead vproj/off/attn/msda)

    const dim3 blk(256);
    const int mt = MROWS >> 6;    // 340

    // 1-3: projections
    gemm_f32<<<dim3(mt * 4), blk, 0, stream>>>(value, W_val,  b_val,  vproj, MROWS, 256,  256, 0);
    gemm_f32<<<dim3(mt * 4), blk, 0, stream>>>(query, W_off,  b_off,  offb,  MROWS, 256,  256, 0);
    gemm_f32<<<dim3(mt * 2), blk, 0, stream>>>(query, W_attn, b_attn, attnb, MROWS, 128,  256, 0);
    // 4: softmax over 16 (in place)
    softmax16<<<dim3(MROWS), dim3(128), 0, stream>>>(attnb);
    // 5: deformable sampling
    msda_sample<<<dim3(MROWS * 8 / 8), blk, 0, stream>>>(vproj, offb, attnb, refs, msda);
    // 6: output projection
    gemm_f32<<<dim3(mt * 4), blk, 0, stream>>>(msda, W_out, b_out, tmp, MROWS, 256, 256, 0);
    // 7: q = value + LN(tmp)
    ln_fused<<<dim3(MROWS / 4), blk, 0, stream>>>(tmp, nullptr, value, ln1g, ln1b, qbuf);
    // 8: f1 = relu(q @ W_ff1 + b_ff1)
    gemm_f32<<<dim3(mt * 16), blk, 0, stream>>>(qbuf, W_ff1, b_ff1, f1, MROWS, DFF, 256, 1);
    // 9: f2 = f1 @ W_ff2 + b_ff2   (tmp reused as f2)
    gemm_f32<<<dim3(mt * 4), blk, 0, stream>>>(f1, W_ff2, b_ff2, tmp, MROWS, 256, DFF, 0);
    // 10: out = LN(q + f2)
    ln_fused<<<dim3(MROWS / 4), blk, 0, stream>>>(qbuf, tmp, nullptr, ln2g, ln2b, out);
}

// Round 2
// 289.497 us; speedup vs baseline: 2.6742x; 2.6742x over previous
//
#include <hip/hip_runtime.h>
#include <cstddef>

// Problem constants (hard-coded from reference):
// D=256, NH=8, NL=4, NP=4, DH=32, B=4, LV=5440, DFF=1024
// SHAPES = {64,64},{32,32},{16,16},{8,8}; level_start = {0,4096,5120,5376}
#define DMODEL 256
#define NHEAD  8
#define BATCH  4
#define LVTOT  5440
#define MROWS  (BATCH * LVTOT)   // 21760 = 128 * 170

typedef __attribute__((ext_vector_type(8))) short short8;
typedef __attribute__((ext_vector_type(4))) float floatx4;

static __device__ __forceinline__ unsigned short f2bf(float f) {
    union { float f; unsigned int u; } v; v.f = f;
    unsigned int u = v.u;
    unsigned int r = (u + 0x7FFFu + ((u >> 16) & 1u)) >> 16;   // RNE
    return (unsigned short)r;
}

// ---------------------------------------------------------------------------
// f32 -> bf16 contiguous convert (float4 per thread)
// ---------------------------------------------------------------------------
__global__ __launch_bounds__(256) void conv_bf16(
    const float* __restrict__ in, unsigned short* __restrict__ out, int n4)
{
    int i = blockIdx.x * 256 + threadIdx.x;
    if (i >= n4) return;
    float4 v = reinterpret_cast<const float4*>(in)[i];
    ushort4 o;
    o.x = f2bf(v.x); o.y = f2bf(v.y); o.z = f2bf(v.z); o.w = f2bf(v.w);
    reinterpret_cast<ushort4*>(out)[i] = o;
}

// ---------------------------------------------------------------------------
// Weight transpose+convert: W f32 [K][N] -> Wt bf16 [N][K]
// ---------------------------------------------------------------------------
__global__ __launch_bounds__(256) void transpose_w(
    const float* __restrict__ W, unsigned short* __restrict__ Wt, int K, int N)
{
    int idx = blockIdx.x * 256 + threadIdx.x;   // output index n*K + k
    if (idx >= K * N) return;
    int k = idx % K;
    int n = idx / K;
    Wt[idx] = f2bf(W[(size_t)k * N + n]);
}

// ---------------------------------------------------------------------------
// bf16 MFMA GEMM: C[M,N] = A[M,K] @ Bt[N,K]^T + bias, optional relu.
// A bf16 row-major, Bt bf16 [N][K] (pre-transposed weight).
// C f32 (optional), Cbf bf16 (optional). M%128==0, N%128==0, K%64==0.
// Block = 256 threads = 4 waves (2x2), tile 128x128, wave tile 64x64, BK=64.
// ---------------------------------------------------------------------------
__global__ __launch_bounds__(256) void gemm_bf16(
    const unsigned short* __restrict__ A, const unsigned short* __restrict__ Bt,
    const float* __restrict__ bias,
    float* __restrict__ C, unsigned short* __restrict__ Cbf,
    int M, int N, int K, int relu)
{
    __shared__ short As[128][72];   // row stride 144 B: banks rotate by 4/row
    __shared__ short Bs[128][72];

    const int tid  = threadIdx.x;
    const int wave = tid >> 6;
    const int lane = tid & 63;
    const int mtiles = M >> 7;
    const int bm = blockIdx.x % mtiles;
    const int bn = blockIdx.x / mtiles;
    const int row0 = bm << 7;
    const int col0 = bn << 7;
    const int wm = (wave >> 1) << 6;   // 0 / 64
    const int wn = (wave & 1) << 6;

    floatx4 acc[4][4];
    #pragma unroll
    for (int i = 0; i < 4; ++i)
        #pragma unroll
        for (int j = 0; j < 4; ++j)
            acc[i][j] = (floatx4){0.f, 0.f, 0.f, 0.f};

    const int lr = tid >> 3;   // 0..31 row block
    const int lc = tid & 7;    // 16B chunk within 64-elem K slice

    for (int k0 = 0; k0 < K; k0 += 64) {
        #pragma unroll
        for (int i = 0; i < 4; ++i) {
            const int r = lr + i * 32;
            const short8 va = *reinterpret_cast<const short8*>(
                &A[(size_t)(row0 + r) * K + k0 + lc * 8]);
            *reinterpret_cast<short8*>(&As[r][lc * 8]) = va;
            const short8 vb = *reinterpret_cast<const short8*>(
                &Bt[(size_t)(col0 + r) * K + k0 + lc * 8]);
            *reinterpret_cast<short8*>(&Bs[r][lc * 8]) = vb;
        }
        __syncthreads();

        #pragma unroll
        for (int kk = 0; kk < 64; kk += 32) {
            short8 af[4], bfr[4];
            #pragma unroll
            for (int i = 0; i < 4; ++i)
                af[i] = *reinterpret_cast<const short8*>(
                    &As[wm + i * 16 + (lane & 15)][kk + (lane >> 4) * 8]);
            #pragma unroll
            for (int j = 0; j < 4; ++j)
                bfr[j] = *reinterpret_cast<const short8*>(
                    &Bs[wn + j * 16 + (lane & 15)][kk + (lane >> 4) * 8]);
            #pragma unroll
            for (int i = 0; i < 4; ++i)
                #pragma unroll
                for (int j = 0; j < 4; ++j)
                    acc[i][j] = __builtin_amdgcn_mfma_f32_16x16x32_bf16(
                        af[i], bfr[j], acc[i][j], 0, 0, 0);
        }
        __syncthreads();
    }

    // Epilogue. C/D layout: col = lane&15, row = (lane>>4)*4 + reg.
    const int rbase = row0 + wm + (lane >> 4) * 4;
    const int cbase = col0 + wn + (lane & 15);
    #pragma unroll
    for (int j = 0; j < 4; ++j) {
        const float bj = bias[cbase + j * 16];
        #pragma unroll
        for (int i = 0; i < 4; ++i) {
            #pragma unroll
            for (int r = 0; r < 4; ++r) {
                float v = acc[i][j][r] + bj;
                if (relu) v = fmaxf(v, 0.f);
                const size_t idx = (size_t)(rbase + i * 16 + r) * N + cbase + j * 16;
                if (C)   C[idx] = v;
                if (Cbf) Cbf[idx] = f2bf(v);
            }
        }
    }
}

// ---------------------------------------------------------------------------
// Softmax over groups of 16 within each row of 128 (in-place).
// ---------------------------------------------------------------------------
__global__ __launch_bounds__(128) void softmax16(float* __restrict__ attn)
{
    const size_t row = blockIdx.x;
    const int t = threadIdx.x;
    float v = attn[row * 128 + t];
    float m = v;
    #pragma unroll
    for (int s = 1; s < 16; s <<= 1) m = fmaxf(m, __shfl_xor(m, s));
    float e = expf(v - m);
    float sum = e;
    #pragma unroll
    for (int s = 1; s < 16; s <<= 1) sum += __shfl_xor(sum, s);
    attn[row * 128 + t] = e / sum;
}

// ---------------------------------------------------------------------------
// Deformable sampling, float4-vectorized: 8 lanes per (b,q,h), lane owns 4 ch.
// vproj f32 [B][LV][256], off f32 [MROWS][256], attn f32 [MROWS][128],
// refs f32 [MROWS][4][2] -> out bf16 [MROWS][256].
// ---------------------------------------------------------------------------
__global__ __launch_bounds__(256) void msda_sample(
    const float* __restrict__ vproj, const float* __restrict__ off,
    const float* __restrict__ attn, const float* __restrict__ refs,
    unsigned short* __restrict__ outbf)
{
    const int l4   = threadIdx.x & 7;                  // float4 slot in head
    const int unit = (blockIdx.x << 5) + (threadIdx.x >> 3);
    const int h  = unit & 7;
    const int bq = unit >> 3;
    const int b  = bq / LVTOT;

    const int lvlN[4] = {64, 32, 16, 8};
    const int lsi[4]  = {0, 4096, 5120, 5376};

    const float* offrow = off  + (size_t)bq * 256 + h * 32;
    const float* arow   = attn + (size_t)bq * 128 + h * 16;
    const float* rrow   = refs + (size_t)bq * 8;
    const float4* vb = reinterpret_cast<const float4*>(
        vproj + (size_t)b * LVTOT * 256 + h * 32) + l4;

    float4 acc = {0.f, 0.f, 0.f, 0.f};
    #pragma unroll
    for (int l = 0; l < 4; ++l) {
        const int   Wi = lvlN[l], Hi = lvlN[l];
        const float Wf = (float)Wi, Hf = (float)Hi;
        const float rx = rrow[l * 2 + 0];
        const float ry = rrow[l * 2 + 1];
        const float4* vlev = vb + (size_t)lsi[l] * 64;   // 256 floats = 64 float4
        #pragma unroll
        for (int p = 0; p < 4; ++p) {
            const float ox = offrow[l * 8 + p * 2 + 0];
            const float oy = offrow[l * 8 + p * 2 + 1];
            const float aw = arow[l * 4 + p];
            const float x = fmaf(rx, Wf, ox) - 0.5f;
            const float y = fmaf(ry, Hf, oy) - 0.5f;
            const float x0 = floorf(x), y0 = floorf(y);
            const float tx = x - x0, ty = y - y0;
            const int xi = (int)x0, yi = (int)y0;
            const float w00 = (1.f - tx) * (1.f - ty);
            const float w10 = tx * (1.f - ty);
            const float w01 = (1.f - tx) * ty;
            const float w11 = tx * ty;
            const bool xin0 = (xi >= 0) && (xi < Wi);
            const bool xin1 = (xi + 1 >= 0) && (xi + 1 < Wi);
            const bool yin0 = (yi >= 0) && (yi < Hi);
            const bool yin1 = (yi + 1 >= 0) && (yi + 1 < Hi);
            float4 s = {0.f, 0.f, 0.f, 0.f};
            if (xin0 && yin0) {
                const float4 g = vlev[(size_t)(yi * Wi + xi) * 64];
                s.x += w00 * g.x; s.y += w00 * g.y; s.z += w00 * g.z; s.w += w00 * g.w;
            }
            if (xin1 && yin0) {
                const float4 g = vlev[(size_t)(yi * Wi + xi + 1) * 64];
                s.x += w10 * g.x; s.y += w10 * g.y; s.z += w10 * g.z; s.w += w10 * g.w;
            }
            if (xin0 && yin1) {
                const float4 g = vlev[(size_t)((yi + 1) * Wi + xi) * 64];
                s.x += w01 * g.x; s.y += w01 * g.y; s.z += w01 * g.z; s.w += w01 * g.w;
            }
            if (xin1 && yin1) {
                const float4 g = vlev[(size_t)((yi + 1) * Wi + xi + 1) * 64];
                s.x += w11 * g.x; s.y += w11 * g.y; s.z += w11 * g.z; s.w += w11 * g.w;
            }
            acc.x += aw * s.x; acc.y += aw * s.y; acc.z += aw * s.z; acc.w += aw * s.w;
        }
    }
    ushort4 o;
    o.x = f2bf(acc.x); o.y = f2bf(acc.y); o.z = f2bf(acc.z); o.w = f2bf(acc.w);
    reinterpret_cast<ushort4*>(outbf + (size_t)bq * 256 + h * 32)[l4] = o;
}

// ---------------------------------------------------------------------------
// LayerNorm over 256 with fused adds:
//   x = x1 + (x2?:0); y = LN(x)*g + b; out = (res?:0) + y; optional bf16 copy.
// ---------------------------------------------------------------------------
__global__ __launch_bounds__(256) void ln_fused(
    const float* __restrict__ x1, const float* __restrict__ x2,
    const float* __restrict__ res,
    const float* __restrict__ g, const float* __restrict__ bta,
    float* __restrict__ out, unsigned short* __restrict__ outbf)
{
    const int row  = (blockIdx.x << 2) + (threadIdx.x >> 6);
    const int lane = threadIdx.x & 63;
    const size_t base = (size_t)row * 256 + lane * 4;

    float4 v = *reinterpret_cast<const float4*>(&x1[base]);
    if (x2) {
        float4 u = *reinterpret_cast<const float4*>(&x2[base]);
        v.x += u.x; v.y += u.y; v.z += u.z; v.w += u.w;
    }
    float s1 = v.x + v.y + v.z + v.w;
    float s2 = v.x * v.x + v.y * v.y + v.z * v.z + v.w * v.w;
    #pragma unroll
    for (int s = 1; s < 64; s <<= 1) {
        s1 += __shfl_xor(s1, s);
        s2 += __shfl_xor(s2, s);
    }
    const float mu  = s1 * (1.f / 256.f);
    const float var = s2 * (1.f / 256.f) - mu * mu;
    const float rstd = rsqrtf(var + 1e-5f);

    float4 gg = *reinterpret_cast<const float4*>(&g[lane * 4]);
    float4 bb = *reinterpret_cast<const float4*>(&bta[lane * 4]);
    float4 o;
    o.x = (v.x - mu) * rstd * gg.x + bb.x;
    o.y = (v.y - mu) * rstd * gg.y + bb.y;
    o.z = (v.z - mu) * rstd * gg.z + bb.z;
    o.w = (v.w - mu) * rstd * gg.w + bb.w;
    if (res) {
        float4 r = *reinterpret_cast<const float4*>(&res[base]);
        o.x += r.x; o.y += r.y; o.z += r.z; o.w += r.w;
    }
    *reinterpret_cast<float4*>(&out[base]) = o;
    if (outbf) {
        ushort4 ob;
        ob.x = f2bf(o.x); ob.y = f2bf(o.y); ob.z = f2bf(o.z); ob.w = f2bf(o.w);
        reinterpret_cast<ushort4*>(outbf + base - lane * 4)[lane] = ob;
    }
}

// ---------------------------------------------------------------------------
extern "C" void kernel_launch(void* const* d_in, const int* in_sizes, int n_in,
                              void* d_out, int out_size, void* d_ws, size_t ws_size,
                              hipStream_t stream)
{
    const float* query  = (const float*)d_in[0];
    const float* refs   = (const float*)d_in[1];
    const float* value  = (const float*)d_in[2];
    const float* W_off  = (const float*)d_in[5];
    const float* b_off  = (const float*)d_in[6];
    const float* W_attn = (const float*)d_in[7];
    const float* b_attn = (const float*)d_in[8];
    const float* W_val  = (const float*)d_in[9];
    const float* b_val  = (const float*)d_in[10];
    const float* W_out  = (const float*)d_in[11];
    const float* b_out  = (const float*)d_in[12];
    const float* ln1g   = (const float*)d_in[13];
    const float* ln1b   = (const float*)d_in[14];
    const float* ln2g   = (const float*)d_in[15];
    const float* ln2b   = (const float*)d_in[16];
    const float* W_ff1  = (const float*)d_in[17];
    const float* b_ff1  = (const float*)d_in[18];
    const float* W_ff2  = (const float*)d_in[19];
    const float* b_ff2  = (const float*)d_in[20];
    float* out = (float*)d_out;
    float* ws  = (float*)d_ws;

    const size_t R = (size_t)MROWS * 256;   // 5,570,560 floats
    // Workspace (floats), lifetime-reused, total 5.6R ≈ 125 MB:
    unsigned short* value_bf = (unsigned short*)(ws);            // [0, .5R) bf16 R el
    unsigned short* msda_bf  = value_bf;                         // reuse after val-proj
    unsigned short* query_bf = (unsigned short*)(ws + R / 2);    // [.5R, 1R)
    unsigned short* wt_base  = (unsigned short*)(ws + R);        // [1R, 1.1R) weights
    float* vproj = ws + R + R / 10;                              // [1.1R, 2.1R)
    float* offb  = vproj + R;                                    // [2.1R, 3.1R)
    float* attnb = offb + R;                                     // [3.1R, 3.6R)
    unsigned short* qbuf_bf = (unsigned short*)attnb;            // reuse after sampling
    float* tmp   = attnb + R / 2;                                // [3.6R, 4.6R)
    float* qbuf  = tmp + R;                                      // [4.6R, 5.6R)
    unsigned short* f1_bf = (unsigned short*)vproj;              // reuse: 4R bf16 el

    // bf16 weight slots (element offsets within wt_base)
    unsigned short* wt_val  = wt_base;             // 256x256
    unsigned short* wt_off  = wt_base + 65536;     // 256x256
    unsigned short* wt_attn = wt_base + 131072;    // 128x256
    unsigned short* wt_out  = wt_base + 163840;    // 256x256
    unsigned short* wt_ff1  = wt_base + 229376;    // 1024x256
    unsigned short* wt_ff2  = wt_base + 491520;    // 256x1024

    const dim3 blk(256);
    const int mt = MROWS >> 7;   // 170

    // 0: input conversions
    conv_bf16<<<dim3((int)(R / 4 / 256)), blk, 0, stream>>>(value, value_bf, (int)(R / 4));
    conv_bf16<<<dim3((int)(R / 4 / 256)), blk, 0, stream>>>(query, query_bf, (int)(R / 4));
    transpose_w<<<dim3(256),  blk, 0, stream>>>(W_val,  wt_val,  256, 256);
    transpose_w<<<dim3(256),  blk, 0, stream>>>(W_off,  wt_off,  256, 256);
    transpose_w<<<dim3(128),  blk, 0, stream>>>(W_attn, wt_attn, 256, 128);
    transpose_w<<<dim3(256),  blk, 0, stream>>>(W_out,  wt_out,  256, 256);
    transpose_w<<<dim3(1024), blk, 0, stream>>>(W_ff1,  wt_ff1,  256, 1024);
    transpose_w<<<dim3(1024), blk, 0, stream>>>(W_ff2,  wt_ff2,  1024, 256);

    // 1-3: projections (bf16 MFMA)
    gemm_bf16<<<dim3(mt * 2), blk, 0, stream>>>(value_bf, wt_val,  b_val,  vproj, nullptr, MROWS, 256, 256, 0);
    gemm_bf16<<<dim3(mt * 2), blk, 0, stream>>>(query_bf, wt_off,  b_off,  offb,  nullptr, MROWS, 256, 256, 0);
    gemm_bf16<<<dim3(mt * 1), blk, 0, stream>>>(query_bf, wt_attn, b_attn, attnb, nullptr, MROWS, 128, 256, 0);
    // 4: softmax
    softmax16<<<dim3(MROWS), dim3(128), 0, stream>>>(attnb);
    // 5: sampling (writes bf16; overwrites value_bf region — value_bf dead)
    msda_sample<<<dim3(MROWS / 4), blk, 0, stream>>>(vproj, offb, attnb, refs, msda_bf);
    // 6: output projection
    gemm_bf16<<<dim3(mt * 2), blk, 0, stream>>>(msda_bf, wt_out, b_out, tmp, nullptr, MROWS, 256, 256, 0);
    // 7: q = value + LN(tmp); bf16 copy for FF1 (attnb region dead)
    ln_fused<<<dim3(MROWS / 4), blk, 0, stream>>>(tmp, nullptr, value, ln1g, ln1b, qbuf, qbuf_bf);
    // 8: f1 = relu(q @ W_ff1), bf16 only (vproj/offb regions dead)
    gemm_bf16<<<dim3(mt * 8), blk, 0, stream>>>(qbuf_bf, wt_ff1, b_ff1, nullptr, f1_bf, MROWS, 1024, 256, 1);
    // 9: f2 = f1 @ W_ff2 -> tmp
    gemm_bf16<<<dim3(mt * 2), blk, 0, stream>>>(f1_bf, wt_ff2, b_ff2, tmp, nullptr, MROWS, 256, 1024, 0);
    // 10: out = LN(qbuf + tmp)
    ln_fused<<<dim3(MROWS / 4), blk, 0, stream>>>(qbuf, tmp, nullptr, ln2g, ln2b, out, nullptr);
}

// Round 3
// 231.305 us; speedup vs baseline: 3.3470x; 1.2516x over previous
//
#include <hip/hip_runtime.h>
#include <cstddef>

// Problem constants (hard-coded from reference):
// D=256, NH=8, NL=4, NP=4, DH=32, B=4, LV=5440, DFF=1024
// SHAPES = {64,64},{32,32},{16,16},{8,8}; level_start = {0,4096,5120,5376}
#define LVTOT  5440
#define MROWS  (4 * LVTOT)   // 21760 = 128 * 170

typedef __attribute__((ext_vector_type(8))) short short8;
typedef __attribute__((ext_vector_type(4))) float floatx4;

static __device__ __forceinline__ unsigned short f2bf(float f) {
    union { float f; unsigned int u; } v; v.f = f;
    unsigned int u = v.u;
    return (unsigned short)((u + 0x7FFFu + ((u >> 16) & 1u)) >> 16);   // RNE
}
static __device__ __forceinline__ float bf2f(unsigned short u) {
    union { unsigned int u; float f; } v; v.u = ((unsigned int)u) << 16; return v.f;
}

// ---------------------------------------------------------------------------
// One-shot weight prep: all six W f32 [K][N] -> bf16 [N][K] at fixed slots.
// Segments (bf16 el): val[0,65536) off[65536,131072) attn[131072,163840)
// out[163840,229376) ff1[229376,491520) ff2[491520,753664). Grid 2944x256.
// ---------------------------------------------------------------------------
__global__ __launch_bounds__(256) void prep_weights(
    const float* __restrict__ Wv, const float* __restrict__ Wo,
    const float* __restrict__ Wa, const float* __restrict__ Wu,
    const float* __restrict__ W1, const float* __restrict__ W2,
    unsigned short* __restrict__ wt)
{
    int idx = blockIdx.x * 256 + threadIdx.x;
    const float* W; int K, N, base;
    if (idx < 131072)      { if (idx < 65536) { W = Wv; base = 0; } else { W = Wo; base = 65536; } K = 256; N = 256; }
    else if (idx < 163840) { W = Wa; base = 131072; K = 256; N = 128; }
    else if (idx < 229376) { W = Wu; base = 163840; K = 256; N = 256; }
    else if (idx < 491520) { W = W1; base = 229376; K = 256; N = 1024; }
    else                   { W = W2; base = 491520; K = 1024; N = 256; }
    int r = idx - base;
    int k = r & (K - 1);
    int n = r / K;
    wt[idx] = f2bf(W[(size_t)k * N + n]);
}

// ---------------------------------------------------------------------------
// bf16 MFMA GEMM: C[M,N] = A[M,K] @ Bt[N,K]^T + bias, optional relu.
// AF32=1: A is f32 (converted to bf16 during LDS staging); else A is bf16.
// C f32 (optional), Cbf bf16 (optional). M%128==0, N%128==0, K%64==0.
// Block = 256 threads = 4 waves (2x2), tile 128x128, wave tile 64x64, BK=64.
// ---------------------------------------------------------------------------
template<int AF32>
__global__ __launch_bounds__(256) void gemm_bf16(
    const void* __restrict__ Av, const unsigned short* __restrict__ Bt,
    const float* __restrict__ bias,
    float* __restrict__ C, unsigned short* __restrict__ Cbf,
    int M, int N, int K, int relu)
{
    __shared__ short As[128][72];   // row stride 144 B: banks rotate by 4/row
    __shared__ short Bs[128][72];

    const int tid  = threadIdx.x;
    const int wave = tid >> 6;
    const int lane = tid & 63;
    const int mtiles = M >> 7;
    const int bm = blockIdx.x % mtiles;
    const int bn = blockIdx.x / mtiles;
    const int row0 = bm << 7;
    const int col0 = bn << 7;
    const int wm = (wave >> 1) << 6;
    const int wn = (wave & 1) << 6;

    floatx4 acc[4][4];
    #pragma unroll
    for (int i = 0; i < 4; ++i)
        #pragma unroll
        for (int j = 0; j < 4; ++j)
            acc[i][j] = (floatx4){0.f, 0.f, 0.f, 0.f};

    const int lr = tid >> 3;   // 0..31 row block
    const int lc = tid & 7;    // 16B chunk within 64-elem K slice

    for (int k0 = 0; k0 < K; k0 += 64) {
        #pragma unroll
        for (int i = 0; i < 4; ++i) {
            const int r = lr + i * 32;
            if (AF32) {
                const float* Af = (const float*)Av;
                const float4 v0 = *reinterpret_cast<const float4*>(
                    &Af[(size_t)(row0 + r) * K + k0 + lc * 8]);
                const float4 v1 = *reinterpret_cast<const float4*>(
                    &Af[(size_t)(row0 + r) * K + k0 + lc * 8 + 4]);
                short8 s;
                s[0] = (short)f2bf(v0.x); s[1] = (short)f2bf(v0.y);
                s[2] = (short)f2bf(v0.z); s[3] = (short)f2bf(v0.w);
                s[4] = (short)f2bf(v1.x); s[5] = (short)f2bf(v1.y);
                s[6] = (short)f2bf(v1.z); s[7] = (short)f2bf(v1.w);
                *reinterpret_cast<short8*>(&As[r][lc * 8]) = s;
            } else {
                const unsigned short* Ab = (const unsigned short*)Av;
                *reinterpret_cast<short8*>(&As[r][lc * 8]) =
                    *reinterpret_cast<const short8*>(
                        &Ab[(size_t)(row0 + r) * K + k0 + lc * 8]);
            }
            *reinterpret_cast<short8*>(&Bs[r][lc * 8]) =
                *reinterpret_cast<const short8*>(
                    &Bt[(size_t)(col0 + r) * K + k0 + lc * 8]);
        }
        __syncthreads();

        #pragma unroll
        for (int kk = 0; kk < 64; kk += 32) {
            short8 af[4], bfr[4];
            #pragma unroll
            for (int i = 0; i < 4; ++i)
                af[i] = *reinterpret_cast<const short8*>(
                    &As[wm + i * 16 + (lane & 15)][kk + (lane >> 4) * 8]);
            #pragma unroll
            for (int j = 0; j < 4; ++j)
                bfr[j] = *reinterpret_cast<const short8*>(
                    &Bs[wn + j * 16 + (lane & 15)][kk + (lane >> 4) * 8]);
            #pragma unroll
            for (int i = 0; i < 4; ++i)
                #pragma unroll
                for (int j = 0; j < 4; ++j)
                    acc[i][j] = __builtin_amdgcn_mfma_f32_16x16x32_bf16(
                        af[i], bfr[j], acc[i][j], 0, 0, 0);
        }
        __syncthreads();
    }

    // Epilogue. C/D layout: col = lane&15, row = (lane>>4)*4 + reg.
    const int rbase = row0 + wm + (lane >> 4) * 4;
    const int cbase = col0 + wn + (lane & 15);
    #pragma unroll
    for (int j = 0; j < 4; ++j) {
        const float bj = bias[cbase + j * 16];
        #pragma unroll
        for (int i = 0; i < 4; ++i) {
            #pragma unroll
            for (int r = 0; r < 4; ++r) {
                float v = acc[i][j][r] + bj;
                if (relu) v = fmaxf(v, 0.f);
                const size_t idx = (size_t)(rbase + i * 16 + r) * N + cbase + j * 16;
                if (C)   C[idx] = v;
                if (Cbf) Cbf[idx] = f2bf(v);
            }
        }
    }
}

// ---------------------------------------------------------------------------
// Deformable sampling + fused softmax-over-16.
// 32 lanes per (b,q,h) unit: lane = l*8 + c; level l owns its 4 points,
// chunk c owns 4 channels. Cross-level reduce via shfl_xor(8,16).
// vproj bf16 [B][LV][256], off f32 [MROWS][256], logits f32 [MROWS][128],
// refs f32 [MROWS][4][2] -> out bf16 [MROWS][256].
// ---------------------------------------------------------------------------
__global__ __launch_bounds__(256) void msda_sample(
    const unsigned short* __restrict__ vproj, const float* __restrict__ off,
    const float* __restrict__ logits, const float* __restrict__ refs,
    unsigned short* __restrict__ outbf)
{
    const int lane32 = threadIdx.x & 31;
    const int l = lane32 >> 3;        // level 0..3
    const int c = lane32 & 7;         // channel chunk 0..7 (4 ch each)
    const int unit = (blockIdx.x << 3) + (threadIdx.x >> 5);
    const int h  = unit & 7;
    const int bq = unit >> 3;
    const int b  = bq / LVTOT;

    const int Nl = 64 >> l;           // W == H per level
    int lsi = 0;
    if (l > 0) lsi = 4096;
    if (l > 1) lsi = 5120;
    if (l > 2) lsi = 5376;

    const float* offrow = off    + (size_t)bq * 256 + h * 32 + l * 8;
    const float* arow   = logits + (size_t)bq * 128 + h * 16 + l * 4;
    const float rx = refs[(size_t)bq * 8 + l * 2 + 0];
    const float ry = refs[(size_t)bq * 8 + l * 2 + 1];
    const unsigned short* vb =
        vproj + ((size_t)b * LVTOT + lsi) * 256 + h * 32 + c * 4;

    // fused softmax over the 16 (l,p) logits of this (bq,h)
    float lg[4];
    #pragma unroll
    for (int p = 0; p < 4; ++p) lg[p] = arow[p];
    float m = fmaxf(fmaxf(lg[0], lg[1]), fmaxf(lg[2], lg[3]));
    m = fmaxf(m, __shfl_xor(m, 8));
    m = fmaxf(m, __shfl_xor(m, 16));
    float e[4]; float s = 0.f;
    #pragma unroll
    for (int p = 0; p < 4; ++p) { e[p] = __expf(lg[p] - m); s += e[p]; }
    s += __shfl_xor(s, 8);
    s += __shfl_xor(s, 16);
    const float inv = 1.f / s;

    const float Nf = (float)Nl;
    float4 acc = {0.f, 0.f, 0.f, 0.f};
    #pragma unroll
    for (int p = 0; p < 4; ++p) {
        const float ox = offrow[p * 2 + 0];
        const float oy = offrow[p * 2 + 1];
        const float aw = e[p] * inv;
        const float x = fmaf(rx, Nf, ox) - 0.5f;
        const float y = fmaf(ry, Nf, oy) - 0.5f;
        const float x0 = floorf(x), y0 = floorf(y);
        const float tx = x - x0, ty = y - y0;
        const int xi = (int)x0, yi = (int)y0;
        const float w00 = (1.f - tx) * (1.f - ty);
        const float w10 = tx * (1.f - ty);
        const float w01 = (1.f - tx) * ty;
        const float w11 = tx * ty;
        const bool xin0 = (xi >= 0) && (xi < Nl);
        const bool xin1 = (xi + 1 >= 0) && (xi + 1 < Nl);
        const bool yin0 = (yi >= 0) && (yi < Nl);
        const bool yin1 = (yi + 1 >= 0) && (yi + 1 < Nl);
        float4 sv = {0.f, 0.f, 0.f, 0.f};
        if (xin0 && yin0) {
            const ushort4 g = *reinterpret_cast<const ushort4*>(vb + (size_t)(yi * Nl + xi) * 256);
            sv.x += w00 * bf2f(g.x); sv.y += w00 * bf2f(g.y);
            sv.z += w00 * bf2f(g.z); sv.w += w00 * bf2f(g.w);
        }
        if (xin1 && yin0) {
            const ushort4 g = *reinterpret_cast<const ushort4*>(vb + (size_t)(yi * Nl + xi + 1) * 256);
            sv.x += w10 * bf2f(g.x); sv.y += w10 * bf2f(g.y);
            sv.z += w10 * bf2f(g.z); sv.w += w10 * bf2f(g.w);
        }
        if (xin0 && yin1) {
            const ushort4 g = *reinterpret_cast<const ushort4*>(vb + (size_t)((yi + 1) * Nl + xi) * 256);
            sv.x += w01 * bf2f(g.x); sv.y += w01 * bf2f(g.y);
            sv.z += w01 * bf2f(g.z); sv.w += w01 * bf2f(g.w);
        }
        if (xin1 && yin1) {
            const ushort4 g = *reinterpret_cast<const ushort4*>(vb + (size_t)((yi + 1) * Nl + xi + 1) * 256);
            sv.x += w11 * bf2f(g.x); sv.y += w11 * bf2f(g.y);
            sv.z += w11 * bf2f(g.z); sv.w += w11 * bf2f(g.w);
        }
        acc.x += aw * sv.x; acc.y += aw * sv.y;
        acc.z += aw * sv.z; acc.w += aw * sv.w;
    }

    // cross-level reduce
    acc.x += __shfl_xor(acc.x, 8);  acc.y += __shfl_xor(acc.y, 8);
    acc.z += __shfl_xor(acc.z, 8);  acc.w += __shfl_xor(acc.w, 8);
    acc.x += __shfl_xor(acc.x, 16); acc.y += __shfl_xor(acc.y, 16);
    acc.z += __shfl_xor(acc.z, 16); acc.w += __shfl_xor(acc.w, 16);

    if (l == 0) {
        ushort4 o;
        o.x = f2bf(acc.x); o.y = f2bf(acc.y); o.z = f2bf(acc.z); o.w = f2bf(acc.w);
        reinterpret_cast<ushort4*>(outbf + (size_t)bq * 256 + h * 32)[c] = o;
    }
}

// ---------------------------------------------------------------------------
// LayerNorm over 256 with fused adds:
//   x = x1 + (x2?:0); y = LN(x)*g + b; out = (res?:0) + y; optional bf16 copy.
// ---------------------------------------------------------------------------
__global__ __launch_bounds__(256) void ln_fused(
    const float* __restrict__ x1, const float* __restrict__ x2,
    const float* __restrict__ res,
    const float* __restrict__ g, const float* __restrict__ bta,
    float* __restrict__ out, unsigned short* __restrict__ outbf)
{
    const int row  = (blockIdx.x << 2) + (threadIdx.x >> 6);
    const int lane = threadIdx.x & 63;
    const size_t base = (size_t)row * 256 + lane * 4;

    float4 v = *reinterpret_cast<const float4*>(&x1[base]);
    if (x2) {
        float4 u = *reinterpret_cast<const float4*>(&x2[base]);
        v.x += u.x; v.y += u.y; v.z += u.z; v.w += u.w;
    }
    float s1 = v.x + v.y + v.z + v.w;
    float s2 = v.x * v.x + v.y * v.y + v.z * v.z + v.w * v.w;
    #pragma unroll
    for (int s = 1; s < 64; s <<= 1) {
        s1 += __shfl_xor(s1, s);
        s2 += __shfl_xor(s2, s);
    }
    const float mu  = s1 * (1.f / 256.f);
    const float var = s2 * (1.f / 256.f) - mu * mu;
    const float rstd = rsqrtf(var + 1e-5f);

    float4 gg = *reinterpret_cast<const float4*>(&g[lane * 4]);
    float4 bb = *reinterpret_cast<const float4*>(&bta[lane * 4]);
    float4 o;
    o.x = (v.x - mu) * rstd * gg.x + bb.x;
    o.y = (v.y - mu) * rstd * gg.y + bb.y;
    o.z = (v.z - mu) * rstd * gg.z + bb.z;
    o.w = (v.w - mu) * rstd * gg.w + bb.w;
    if (res) {
        float4 r = *reinterpret_cast<const float4*>(&res[base]);
        o.x += r.x; o.y += r.y; o.z += r.z; o.w += r.w;
    }
    *reinterpret_cast<float4*>(&out[base]) = o;
    if (outbf) {
        ushort4 ob;
        ob.x = f2bf(o.x); ob.y = f2bf(o.y); ob.z = f2bf(o.z); ob.w = f2bf(o.w);
        reinterpret_cast<ushort4*>(outbf + base - lane * 4)[lane] = ob;
    }
}

// ---------------------------------------------------------------------------
extern "C" void kernel_launch(void* const* d_in, const int* in_sizes, int n_in,
                              void* d_out, int out_size, void* d_ws, size_t ws_size,
                              hipStream_t stream)
{
    const float* query  = (const float*)d_in[0];
    const float* refs   = (const float*)d_in[1];
    const float* value  = (const float*)d_in[2];
    const float* W_off  = (const float*)d_in[5];
    const float* b_off  = (const float*)d_in[6];
    const float* W_attn = (const float*)d_in[7];
    const float* b_attn = (const float*)d_in[8];
    const float* W_val  = (const float*)d_in[9];
    const float* b_val  = (const float*)d_in[10];
    const float* W_out  = (const float*)d_in[11];
    const float* b_out  = (const float*)d_in[12];
    const float* ln1g   = (const float*)d_in[13];
    const float* ln1b   = (const float*)d_in[14];
    const float* ln2g   = (const float*)d_in[15];
    const float* ln2b   = (const float*)d_in[16];
    const float* W_ff1  = (const float*)d_in[17];
    const float* b_ff1  = (const float*)d_in[18];
    const float* W_ff2  = (const float*)d_in[19];
    const float* b_ff2  = (const float*)d_in[20];
    float* out = (float*)d_out;
    float* ws  = (float*)d_ws;

    const size_t R = (size_t)MROWS * 256;   // 5,570,560 floats
    const size_t WTF = 376832;              // 753,664 bf16 weights (in floats)
    // Workspace (float offsets), lifetime-reused, total ~5.07R ≈ 113 MB:
    unsigned short* wt_base = (unsigned short*)ws;
    float* offb  = ws + WTF;                          // R
    float* attnb = offb + R;                          // R/2 (logits)
    unsigned short* vproj_bf = (unsigned short*)(attnb + R / 2);   // R bf16
    unsigned short* msda_bf  = (unsigned short*)(attnb + R);       // R bf16
    float* tmp   = attnb + R + R / 2;                 // R
    float* qbuf  = tmp + R;                           // R
    unsigned short* qbuf_bf = (unsigned short*)(qbuf + R);         // R bf16
    unsigned short* f1_bf = (unsigned short*)offb;    // 4R bf16 (reuse dead region)

    unsigned short* wt_val  = wt_base;
    unsigned short* wt_off  = wt_base + 65536;
    unsigned short* wt_attn = wt_base + 131072;
    unsigned short* wt_out  = wt_base + 163840;
    unsigned short* wt_ff1  = wt_base + 229376;
    unsigned short* wt_ff2  = wt_base + 491520;

    const dim3 blk(256);
    const int mt = MROWS >> 7;   // 170

    // 0: weight prep (one launch)
    prep_weights<<<dim3(2944), blk, 0, stream>>>(W_val, W_off, W_attn, W_out, W_ff1, W_ff2, wt_base);

    // 1-3: projections (bf16 MFMA, f32 A staged inline)
    gemm_bf16<1><<<dim3(mt * 2), blk, 0, stream>>>(value, wt_val,  b_val,  nullptr, vproj_bf, MROWS, 256, 256, 0);
    gemm_bf16<1><<<dim3(mt * 2), blk, 0, stream>>>(query, wt_off,  b_off,  offb,    nullptr,  MROWS, 256, 256, 0);
    gemm_bf16<1><<<dim3(mt * 1), blk, 0, stream>>>(query, wt_attn, b_attn, attnb,   nullptr,  MROWS, 128, 256, 0);
    // 4: sampling (softmax fused; logits in attnb)
    msda_sample<<<dim3(MROWS), blk, 0, stream>>>(vproj_bf, offb, attnb, refs, msda_bf);
    // 5: output projection
    gemm_bf16<0><<<dim3(mt * 2), blk, 0, stream>>>(msda_bf, wt_out, b_out, tmp, nullptr, MROWS, 256, 256, 0);
    // 6: q = value + LN(tmp); bf16 copy for FF1
    ln_fused<<<dim3(MROWS / 4), blk, 0, stream>>>(tmp, nullptr, value, ln1g, ln1b, qbuf, qbuf_bf);
    // 7: f1 = relu(q @ W_ff1), bf16 (offb/attnb/vproj/msda regions dead)
    gemm_bf16<0><<<dim3(mt * 8), blk, 0, stream>>>(qbuf_bf, wt_ff1, b_ff1, nullptr, f1_bf, MROWS, 1024, 256, 1);
    // 8: f2 = f1 @ W_ff2 -> tmp
    gemm_bf16<0><<<dim3(mt * 2), blk, 0, stream>>>(f1_bf, wt_ff2, b_ff2, tmp, nullptr, MROWS, 256, 1024, 0);
    // 9: out = LN(qbuf + tmp)
    ln_fused<<<dim3(MROWS / 4), blk, 0, stream>>>(qbuf, tmp, nullptr, ln2g, ln2b, out, nullptr);
}

// Round 4
// 205.147 us; speedup vs baseline: 3.7737x; 1.1275x over previous
//
#include <hip/hip_runtime.h>
#include <cstddef>

// Problem constants (hard-coded from reference):
// D=256, NH=8, NL=4, NP=4, DH=32, B=4, LV=5440, DFF=1024
// SHAPES = {64,64},{32,32},{16,16},{8,8}; level_start = {0,4096,5120,5376}
#define LVTOT  5440
#define MROWS  (4 * LVTOT)   // 21760 = 128 * 170

typedef __attribute__((ext_vector_type(8))) short short8;
typedef __attribute__((ext_vector_type(4))) float floatx4;

static __device__ __forceinline__ unsigned short f2bf(float f) {
    union { float f; unsigned int u; } v; v.f = f;
    unsigned int u = v.u;
    return (unsigned short)((u + 0x7FFFu + ((u >> 16) & 1u)) >> 16);   // RNE
}
static __device__ __forceinline__ float bf2f(unsigned short u) {
    union { unsigned int u; float f; } v; v.u = ((unsigned int)u) << 16; return v.f;
}
static __device__ __forceinline__ float bf2fs(short s) { return bf2f((unsigned short)s); }

#define GLOAD_LDS16(gptr, lptr)                                          \
    __builtin_amdgcn_global_load_lds(                                    \
        (const __attribute__((address_space(1))) void*)(gptr),           \
        (__attribute__((address_space(3))) void*)(lptr), 16, 0, 0)

// ---------------------------------------------------------------------------
// One-shot weight prep, all f32 [K][N] -> bf16 [N][K] at fixed slots:
//   val[0,65536) oa[65536,163840) (off rows 0..255 + attn rows 256..383)
//   out[163840,229376) ff1[229376,491520) ff2[491520,753664)
// plus bias_oa[384] floats (b_off ++ b_attn). Grid 2946x256.
// ---------------------------------------------------------------------------
__global__ __launch_bounds__(256) void prep_weights(
    const float* __restrict__ Wv, const float* __restrict__ Wo,
    const float* __restrict__ Wa, const float* __restrict__ Wu,
    const float* __restrict__ W1, const float* __restrict__ W2,
    const float* __restrict__ bo, const float* __restrict__ ba,
    unsigned short* __restrict__ wt, float* __restrict__ bias_oa)
{
    int idx = blockIdx.x * 256 + threadIdx.x;
    if (idx >= 754048) return;
    if (idx >= 753664) {               // bias concat
        int j = idx - 753664;
        bias_oa[j] = (j < 256) ? bo[j] : ba[j - 256];
        return;
    }
    float src;
    if (idx < 65536) {
        int r = idx; src = Wv[(size_t)(r & 255) * 256 + (r >> 8)];
    } else if (idx < 163840) {
        int r = idx - 65536; int n = r >> 8, k = r & 255;
        src = (n < 256) ? Wo[(size_t)k * 256 + n] : Wa[(size_t)k * 128 + (n - 256)];
    } else if (idx < 229376) {
        int r = idx - 163840; src = Wu[(size_t)(r & 255) * 256 + (r >> 8)];
    } else if (idx < 491520) {
        int r = idx - 229376; src = W1[(size_t)(r & 255) * 1024 + (r >> 8)];
    } else {
        int r = idx - 491520; src = W2[(size_t)(r & 1023) * 256 + (r >> 10)];
    }
    wt[idx] = f2bf(src);
}

// ---------------------------------------------------------------------------
// MFMA GEMM, A = f32 (converted during reg-staging): C = A @ Bt^T + bias.
// Bt bf16 [N][K]. Tile 128x128, 4 waves (2x2), BK=64, padded LDS.
// ---------------------------------------------------------------------------
__global__ __launch_bounds__(256) void gemm_af32(
    const float* __restrict__ A, const unsigned short* __restrict__ Bt,
    const float* __restrict__ bias,
    float* __restrict__ C, unsigned short* __restrict__ Cbf,
    int M, int N, int K, int relu)
{
    __shared__ short As[128][72];
    __shared__ short Bs[128][72];

    const int tid  = threadIdx.x;
    const int wave = tid >> 6;
    const int lane = tid & 63;
    const int mtiles = M >> 7;
    const int bm = blockIdx.x % mtiles;
    const int bn = blockIdx.x / mtiles;
    const int row0 = bm << 7;
    const int col0 = bn << 7;
    const int wm = (wave >> 1) << 6;
    const int wn = (wave & 1) << 6;

    floatx4 acc[4][4];
    #pragma unroll
    for (int i = 0; i < 4; ++i)
        #pragma unroll
        for (int j = 0; j < 4; ++j)
            acc[i][j] = (floatx4){0.f, 0.f, 0.f, 0.f};

    const int lr = tid >> 3;
    const int lc = tid & 7;

    for (int k0 = 0; k0 < K; k0 += 64) {
        #pragma unroll
        for (int i = 0; i < 4; ++i) {
            const int r = lr + i * 32;
            const float4 v0 = *reinterpret_cast<const float4*>(
                &A[(size_t)(row0 + r) * K + k0 + lc * 8]);
            const float4 v1 = *reinterpret_cast<const float4*>(
                &A[(size_t)(row0 + r) * K + k0 + lc * 8 + 4]);
            short8 s;
            s[0] = (short)f2bf(v0.x); s[1] = (short)f2bf(v0.y);
            s[2] = (short)f2bf(v0.z); s[3] = (short)f2bf(v0.w);
            s[4] = (short)f2bf(v1.x); s[5] = (short)f2bf(v1.y);
            s[6] = (short)f2bf(v1.z); s[7] = (short)f2bf(v1.w);
            *reinterpret_cast<short8*>(&As[r][lc * 8]) = s;
            *reinterpret_cast<short8*>(&Bs[r][lc * 8]) =
                *reinterpret_cast<const short8*>(
                    &Bt[(size_t)(col0 + r) * K + k0 + lc * 8]);
        }
        __syncthreads();

        #pragma unroll
        for (int kk = 0; kk < 64; kk += 32) {
            short8 af[4], bfr[4];
            #pragma unroll
            for (int i = 0; i < 4; ++i)
                af[i] = *reinterpret_cast<const short8*>(
                    &As[wm + i * 16 + (lane & 15)][kk + (lane >> 4) * 8]);
            #pragma unroll
            for (int j = 0; j < 4; ++j)
                bfr[j] = *reinterpret_cast<const short8*>(
                    &Bs[wn + j * 16 + (lane & 15)][kk + (lane >> 4) * 8]);
            #pragma unroll
            for (int i = 0; i < 4; ++i)
                #pragma unroll
                for (int j = 0; j < 4; ++j)
                    acc[i][j] = __builtin_amdgcn_mfma_f32_16x16x32_bf16(
                        af[i], bfr[j], acc[i][j], 0, 0, 0);
        }
        __syncthreads();
    }

    const int rbase = row0 + wm + (lane >> 4) * 4;
    const int cbase = col0 + wn + (lane & 15);
    #pragma unroll
    for (int j = 0; j < 4; ++j) {
        const float bj = bias[cbase + j * 16];
        #pragma unroll
        for (int i = 0; i < 4; ++i) {
            #pragma unroll
            for (int r = 0; r < 4; ++r) {
                float v = acc[i][j][r] + bj;
                if (relu) v = fmaxf(v, 0.f);
                const size_t idx = (size_t)(rbase + i * 16 + r) * N + cbase + j * 16;
                if (C)   C[idx] = v;
                if (Cbf) Cbf[idx] = f2bf(v);
            }
        }
    }
}

// ---------------------------------------------------------------------------
// MFMA GEMM, A = bf16, staged via global_load_lds width-16 (m97 structure).
// Linear LDS [128][64]; wave-uniform base + lane*16 matches (lr,lc) layout.
// ---------------------------------------------------------------------------
__global__ __launch_bounds__(256) void gemm_lds(
    const unsigned short* __restrict__ A, const unsigned short* __restrict__ Bt,
    const float* __restrict__ bias,
    float* __restrict__ C, unsigned short* __restrict__ Cbf,
    int M, int N, int K, int relu)
{
    __shared__ short As[128 * 64];
    __shared__ short Bs[128 * 64];

    const int tid  = threadIdx.x;
    const int wave = tid >> 6;
    const int lane = tid & 63;
    const int mtiles = M >> 7;
    const int bm = blockIdx.x % mtiles;
    const int bn = blockIdx.x / mtiles;
    const int row0 = bm << 7;
    const int col0 = bn << 7;
    const int wm = (wave >> 1) << 6;
    const int wn = (wave & 1) << 6;

    floatx4 acc[4][4];
    #pragma unroll
    for (int i = 0; i < 4; ++i)
        #pragma unroll
        for (int j = 0; j < 4; ++j)
            acc[i][j] = (floatx4){0.f, 0.f, 0.f, 0.f};

    const int lr = tid >> 3;        // 0..31
    const int lc = tid & 7;
    const unsigned short* Ag = A  + (size_t)(row0 + lr) * K + lc * 8;
    const unsigned short* Bg = Bt + (size_t)(col0 + lr) * K + lc * 8;

    for (int k0 = 0; k0 < K; k0 += 64) {
        #pragma unroll
        for (int i = 0; i < 4; ++i) {
            GLOAD_LDS16(Ag + (size_t)(i * 32) * K + k0, &As[(wave * 8 + i * 32) * 64]);
            GLOAD_LDS16(Bg + (size_t)(i * 32) * K + k0, &Bs[(wave * 8 + i * 32) * 64]);
        }
        __syncthreads();   // drains vmcnt(0) before barrier

        #pragma unroll
        for (int kk = 0; kk < 64; kk += 32) {
            short8 af[4], bfr[4];
            #pragma unroll
            for (int i = 0; i < 4; ++i)
                af[i] = *reinterpret_cast<const short8*>(
                    &As[(wm + i * 16 + (lane & 15)) * 64 + kk + (lane >> 4) * 8]);
            #pragma unroll
            for (int j = 0; j < 4; ++j)
                bfr[j] = *reinterpret_cast<const short8*>(
                    &Bs[(wn + j * 16 + (lane & 15)) * 64 + kk + (lane >> 4) * 8]);
            #pragma unroll
            for (int i = 0; i < 4; ++i)
                #pragma unroll
                for (int j = 0; j < 4; ++j)
                    acc[i][j] = __builtin_amdgcn_mfma_f32_16x16x32_bf16(
                        af[i], bfr[j], acc[i][j], 0, 0, 0);
        }
        __syncthreads();
    }

    const int rbase = row0 + wm + (lane >> 4) * 4;
    const int cbase = col0 + wn + (lane & 15);
    #pragma unroll
    for (int j = 0; j < 4; ++j) {
        const float bj = bias[cbase + j * 16];
        #pragma unroll
        for (int i = 0; i < 4; ++i) {
            #pragma unroll
            for (int r = 0; r < 4; ++r) {
                float v = acc[i][j][r] + bj;
                if (relu) v = fmaxf(v, 0.f);
                const size_t idx = (size_t)(rbase + i * 16 + r) * N + cbase + j * 16;
                if (C)   C[idx] = v;
                if (Cbf) Cbf[idx] = f2bf(v);
            }
        }
    }
}

// ---------------------------------------------------------------------------
// Deformable sampling + fused softmax. 32 lanes per (b,q,h): lane = l*8+c.
// Branch-free corners: validity via unsigned cmp, clamp via &(Nl-1) (pow2),
// weight zeroed by select. All 16 gathers batched for ILP.
// vproj bf16 [B][LV][256]; oa bf16 [MROWS][384] (off 0..255, logits 256..383);
// refs f32 [MROWS][4][2] -> out bf16 [MROWS][256].
// ---------------------------------------------------------------------------
__global__ __launch_bounds__(256) void msda_sample(
    const unsigned short* __restrict__ vproj,
    const unsigned short* __restrict__ oa,
    const float* __restrict__ refs,
    unsigned short* __restrict__ outbf)
{
    const int lane32 = threadIdx.x & 31;
    const int l = lane32 >> 3;         // level
    const int c = lane32 & 7;          // 4-channel chunk
    const int unit = (blockIdx.x << 3) + (threadIdx.x >> 5);
    const int h  = unit & 7;
    const int bq = unit >> 3;
    const int b  = bq / LVTOT;         // const-div -> magic mul

    const int sl  = 6 - l;             // log2(level size)
    const int Nl  = 1 << sl;
    const int msk = Nl - 1;
    const int lsi = (l == 0) ? 0 : (l == 1) ? 4096 : (l == 2) ? 5120 : 5376;

    const size_t oabase = (size_t)bq * 384;
    const short8  offv = *reinterpret_cast<const short8*>(oa + oabase + h * 32 + l * 8);
    const ushort4 lgu  = *reinterpret_cast<const ushort4*>(oa + oabase + 256 + h * 16 + l * 4);
    const float2  rr   = *reinterpret_cast<const float2*>(refs + (size_t)bq * 8 + l * 2);
    const unsigned short* vb =
        vproj + ((size_t)b * LVTOT + lsi) * 256 + h * 32 + c * 4;

    // softmax over 16 logits (4 local + cross-level shfl)
    float lg[4] = { bf2f(lgu.x), bf2f(lgu.y), bf2f(lgu.z), bf2f(lgu.w) };
    float m = fmaxf(fmaxf(lg[0], lg[1]), fmaxf(lg[2], lg[3]));
    m = fmaxf(m, __shfl_xor(m, 8));
    m = fmaxf(m, __shfl_xor(m, 16));
    float e[4]; float s = 0.f;
    #pragma unroll
    for (int p = 0; p < 4; ++p) { e[p] = __expf(lg[p] - m); s += e[p]; }
    s += __shfl_xor(s, 8);
    s += __shfl_xor(s, 16);
    const float inv = 1.f / s;

    const float Nf = (float)Nl;
    int   idxs[16];
    float wts[16];
    #pragma unroll
    for (int p = 0; p < 4; ++p) {
        const float ox = bf2fs(offv[p * 2 + 0]);
        const float oy = bf2fs(offv[p * 2 + 1]);
        const float aw = e[p] * inv;
        const float x = fmaf(rr.x, Nf, ox) - 0.5f;
        const float y = fmaf(rr.y, Nf, oy) - 0.5f;
        const float xf = floorf(x), yf = floorf(y);
        const float tx = x - xf, ty = y - yf;
        const int xi = (int)xf, yi = (int)yf;
        const bool x0v = (unsigned)xi < (unsigned)Nl;
        const bool x1v = (unsigned)(xi + 1) < (unsigned)Nl;
        const bool y0v = (unsigned)yi < (unsigned)Nl;
        const bool y1v = (unsigned)(yi + 1) < (unsigned)Nl;
        const float w0x = (1.f - tx) * aw, w1x = tx * aw;
        const int xm0 = xi & msk, xm1 = (xi + 1) & msk;
        const int ym0 = (yi & msk) << sl, ym1 = ((yi + 1) & msk) << sl;
        wts[p * 4 + 0] = (x0v & y0v) ? w0x * (1.f - ty) : 0.f;
        wts[p * 4 + 1] = (x1v & y0v) ? w1x * (1.f - ty) : 0.f;
        wts[p * 4 + 2] = (x0v & y1v) ? w0x * ty : 0.f;
        wts[p * 4 + 3] = (x1v & y1v) ? w1x * ty : 0.f;
        idxs[p * 4 + 0] = (ym0 | xm0) << 8;
        idxs[p * 4 + 1] = (ym0 | xm1) << 8;
        idxs[p * 4 + 2] = (ym1 | xm0) << 8;
        idxs[p * 4 + 3] = (ym1 | xm1) << 8;
    }

    ushort4 g[16];
    #pragma unroll
    for (int t = 0; t < 16; ++t)
        g[t] = *reinterpret_cast<const ushort4*>(vb + idxs[t]);

    float4 acc = {0.f, 0.f, 0.f, 0.f};
    #pragma unroll
    for (int t = 0; t < 16; ++t) {
        const float w = wts[t];
        acc.x = fmaf(w, bf2f(g[t].x), acc.x);
        acc.y = fmaf(w, bf2f(g[t].y), acc.y);
        acc.z = fmaf(w, bf2f(g[t].z), acc.z);
        acc.w = fmaf(w, bf2f(g[t].w), acc.w);
    }

    // cross-level reduce
    acc.x += __shfl_xor(acc.x, 8);  acc.y += __shfl_xor(acc.y, 8);
    acc.z += __shfl_xor(acc.z, 8);  acc.w += __shfl_xor(acc.w, 8);
    acc.x += __shfl_xor(acc.x, 16); acc.y += __shfl_xor(acc.y, 16);
    acc.z += __shfl_xor(acc.z, 16); acc.w += __shfl_xor(acc.w, 16);

    if (l == 0) {
        ushort4 o;
        o.x = f2bf(acc.x); o.y = f2bf(acc.y); o.z = f2bf(acc.z); o.w = f2bf(acc.w);
        reinterpret_cast<ushort4*>(outbf + (size_t)bq * 256 + h * 32)[c] = o;
    }
}

// ---------------------------------------------------------------------------
// LayerNorm over 256 with fused adds:
//   x = x1 + (x2?:0); y = LN(x)*g + b; out = (res?:0) + y; optional bf16 copy.
// ---------------------------------------------------------------------------
__global__ __launch_bounds__(256) void ln_fused(
    const float* __restrict__ x1, const float* __restrict__ x2,
    const float* __restrict__ res,
    const float* __restrict__ g, const float* __restrict__ bta,
    float* __restrict__ out, unsigned short* __restrict__ outbf)
{
    const int row  = (blockIdx.x << 2) + (threadIdx.x >> 6);
    const int lane = threadIdx.x & 63;
    const size_t base = (size_t)row * 256 + lane * 4;

    float4 v = *reinterpret_cast<const float4*>(&x1[base]);
    if (x2) {
        float4 u = *reinterpret_cast<const float4*>(&x2[base]);
        v.x += u.x; v.y += u.y; v.z += u.z; v.w += u.w;
    }
    float s1 = v.x + v.y + v.z + v.w;
    float s2 = v.x * v.x + v.y * v.y + v.z * v.z + v.w * v.w;
    #pragma unroll
    for (int s = 1; s < 64; s <<= 1) {
        s1 += __shfl_xor(s1, s);
        s2 += __shfl_xor(s2, s);
    }
    const float mu  = s1 * (1.f / 256.f);
    const float var = s2 * (1.f / 256.f) - mu * mu;
    const float rstd = rsqrtf(var + 1e-5f);

    float4 gg = *reinterpret_cast<const float4*>(&g[lane * 4]);
    float4 bb = *reinterpret_cast<const float4*>(&bta[lane * 4]);
    float4 o;
    o.x = (v.x - mu) * rstd * gg.x + bb.x;
    o.y = (v.y - mu) * rstd * gg.y + bb.y;
    o.z = (v.z - mu) * rstd * gg.z + bb.z;
    o.w = (v.w - mu) * rstd * gg.w + bb.w;
    if (res) {
        float4 r = *reinterpret_cast<const float4*>(&res[base]);
        o.x += r.x; o.y += r.y; o.z += r.z; o.w += r.w;
    }
    *reinterpret_cast<float4*>(&out[base]) = o;
    if (outbf) {
        ushort4 ob;
        ob.x = f2bf(o.x); ob.y = f2bf(o.y); ob.z = f2bf(o.z); ob.w = f2bf(o.w);
        reinterpret_cast<ushort4*>(outbf + base - lane * 4)[lane] = ob;
    }
}

// ---------------------------------------------------------------------------
extern "C" void kernel_launch(void* const* d_in, const int* in_sizes, int n_in,
                              void* d_out, int out_size, void* d_ws, size_t ws_size,
                              hipStream_t stream)
{
    const float* query  = (const float*)d_in[0];
    const float* refs   = (const float*)d_in[1];
    const float* value  = (const float*)d_in[2];
    const float* W_off  = (const float*)d_in[5];
    const float* b_off  = (const float*)d_in[6];
    const float* W_attn = (const float*)d_in[7];
    const float* b_attn = (const float*)d_in[8];
    const float* W_val  = (const float*)d_in[9];
    const float* b_val  = (const float*)d_in[10];
    const float* W_out  = (const float*)d_in[11];
    const float* b_out  = (const float*)d_in[12];
    const float* ln1g   = (const float*)d_in[13];
    const float* ln1b   = (const float*)d_in[14];
    const float* ln2g   = (const float*)d_in[15];
    const float* ln2b   = (const float*)d_in[16];
    const float* W_ff1  = (const float*)d_in[17];
    const float* b_ff1  = (const float*)d_in[18];
    const float* W_ff2  = (const float*)d_in[19];
    const float* b_ff2  = (const float*)d_in[20];
    float* out = (float*)d_out;
    float* ws  = (float*)d_ws;

    const size_t R = (size_t)MROWS * 256;   // 5,570,560 floats
    // Workspace (float offsets), lifetime-reused, total ~4.87R ≈ 102 MB:
    unsigned short* wt_base = (unsigned short*)ws;         // 753,664 bf16
    float* bias_oa = ws + 376832;                          // 384 (pad to 512)
    const size_t base0 = 377344;
    unsigned short* oa_bf    = (unsigned short*)(ws + base0);              // 0.75R fl
    unsigned short* vproj_bf = (unsigned short*)(ws + base0 + 3 * R / 4);  // 0.5R fl
    unsigned short* msda_bf  = (unsigned short*)(ws + base0 + 5 * R / 4);  // 0.5R fl
    // f1x pad: [base0+1.75R, base0+2R)
    float* tmp  = ws + base0 + 2 * R;                       // R
    float* qbuf = ws + base0 + 3 * R;                       // R
    unsigned short* qbuf_bf = (unsigned short*)(ws + base0 + 4 * R);       // 0.5R fl
    unsigned short* f1_bf = oa_bf;   // spans 2R floats over dead oa/vproj/msda/pad

    unsigned short* wt_val = wt_base;
    unsigned short* wt_oa  = wt_base + 65536;
    unsigned short* wt_out = wt_base + 163840;
    unsigned short* wt_ff1 = wt_base + 229376;
    unsigned short* wt_ff2 = wt_base + 491520;

    const dim3 blk(256);
    const int mt = MROWS >> 7;   // 170

    // 0: weight prep
    prep_weights<<<dim3(2946), blk, 0, stream>>>(W_val, W_off, W_attn, W_out,
                                                 W_ff1, W_ff2, b_off, b_attn,
                                                 wt_base, bias_oa);
    // 1: value projection (f32 A), bf16 out
    gemm_af32<<<dim3(mt * 2), blk, 0, stream>>>(value, wt_val, b_val,
                                                nullptr, vproj_bf, MROWS, 256, 256, 0);
    // 2: merged offsets+logits projection (f32 A), bf16 out, N=384
    gemm_af32<<<dim3(mt * 3), blk, 0, stream>>>(query, wt_oa, bias_oa,
                                                nullptr, oa_bf, MROWS, 384, 256, 0);
    // 3: sampling (softmax fused)
    msda_sample<<<dim3(MROWS), blk, 0, stream>>>(vproj_bf, oa_bf, refs, msda_bf);
    // 4: output projection (gload_lds path)
    gemm_lds<<<dim3(mt * 2), blk, 0, stream>>>(msda_bf, wt_out, b_out,
                                               tmp, nullptr, MROWS, 256, 256, 0);
    // 5: q = value + LN(tmp); bf16 copy for FF1
    ln_fused<<<dim3(MROWS / 4), blk, 0, stream>>>(tmp, nullptr, value, ln1g, ln1b, qbuf, qbuf_bf);
    // 6: f1 = relu(q @ W_ff1), bf16 (oa/vproj/msda regions dead)
    gemm_lds<<<dim3(mt * 8), blk, 0, stream>>>(qbuf_bf, wt_ff1, b_ff1,
                                               nullptr, f1_bf, MROWS, 1024, 256, 1);
    // 7: f2 = f1 @ W_ff2 -> tmp
    gemm_lds<<<dim3(mt * 2), blk, 0, stream>>>(f1_bf, wt_ff2, b_ff2,
                                               tmp, nullptr, MROWS, 256, 1024, 0);
    // 8: out = LN(qbuf + tmp)
    ln_fused<<<dim3(MROWS / 4), blk, 0, stream>>>(qbuf, tmp, nullptr, ln2g, ln2b, out, nullptr);
}

// Round 5
// 178.274 us; speedup vs baseline: 4.3426x; 1.1507x over previous
//
#include <hip/hip_runtime.h>
#include <cstddef>

// Problem constants (hard-coded from reference):
// D=256, NH=8, NL=4, NP=4, DH=32, B=4, LV=5440, DFF=1024
// SHAPES = {64,64},{32,32},{16,16},{8,8}; level_start = {0,4096,5120,5376}
#define LVTOT  5440
#define MROWS  (4 * LVTOT)   // 21760 = 128 * 170

typedef __attribute__((ext_vector_type(8))) short short8;
typedef __attribute__((ext_vector_type(4))) float floatx4;

static __device__ __forceinline__ unsigned short f2bf(float f) {
    union { float f; unsigned int u; } v; v.f = f;
    unsigned int u = v.u;
    return (unsigned short)((u + 0x7FFFu + ((u >> 16) & 1u)) >> 16);   // RNE
}
static __device__ __forceinline__ float bf2f(unsigned short u) {
    union { unsigned int u; float f; } v; v.u = ((unsigned int)u) << 16; return v.f;
}
static __device__ __forceinline__ float bf2fs(short s) { return bf2f((unsigned short)s); }

#define GLOAD_LDS16(gptr, lptr)                                          \
    __builtin_amdgcn_global_load_lds(                                    \
        (const __attribute__((address_space(1))) void*)(gptr),           \
        (__attribute__((address_space(3))) void*)(lptr), 16, 0, 0)

// ---------------------------------------------------------------------------
// One-shot weight prep, all f32 [K][N] -> bf16 [N][K] at fixed slots:
//   val[0,65536) oa[65536,163840) (off rows 0..255 + attn rows 256..383)
//   out[163840,229376) ff1[229376,491520) ff2[491520,753664)
// plus bias_oa[384] floats (b_off ++ b_attn). Grid 2946x256.
// ---------------------------------------------------------------------------
__global__ __launch_bounds__(256) void prep_weights(
    const float* __restrict__ Wv, const float* __restrict__ Wo,
    const float* __restrict__ Wa, const float* __restrict__ Wu,
    const float* __restrict__ W1, const float* __restrict__ W2,
    const float* __restrict__ bo, const float* __restrict__ ba,
    unsigned short* __restrict__ wt, float* __restrict__ bias_oa)
{
    int idx = blockIdx.x * 256 + threadIdx.x;
    if (idx >= 754048) return;
    if (idx >= 753664) {               // bias concat
        int j = idx - 753664;
        bias_oa[j] = (j < 256) ? bo[j] : ba[j - 256];
        return;
    }
    float src;
    if (idx < 65536) {
        int r = idx; src = Wv[(size_t)(r & 255) * 256 + (r >> 8)];
    } else if (idx < 163840) {
        int r = idx - 65536; int n = r >> 8, k = r & 255;
        src = (n < 256) ? Wo[(size_t)k * 256 + n] : Wa[(size_t)k * 128 + (n - 256)];
    } else if (idx < 229376) {
        int r = idx - 163840; src = Wu[(size_t)(r & 255) * 256 + (r >> 8)];
    } else if (idx < 491520) {
        int r = idx - 229376; src = W1[(size_t)(r & 255) * 1024 + (r >> 8)];
    } else {
        int r = idx - 491520; src = W2[(size_t)(r & 1023) * 256 + (r >> 10)];
    }
    wt[idx] = f2bf(src);
}

// ---------------------------------------------------------------------------
// MFMA GEMM, A = f32 (converted during reg-staging): C = A @ Bt^T + bias.
// Bt bf16 [N][K]. Tile 128x128, 4 waves (2x2), BK=64, padded LDS.
// ---------------------------------------------------------------------------
__global__ __launch_bounds__(256) void gemm_af32(
    const float* __restrict__ A, const unsigned short* __restrict__ Bt,
    const float* __restrict__ bias,
    float* __restrict__ C, unsigned short* __restrict__ Cbf,
    int M, int N, int K, int relu)
{
    __shared__ short As[128][72];
    __shared__ short Bs[128][72];

    const int tid  = threadIdx.x;
    const int wave = tid >> 6;
    const int lane = tid & 63;
    const int mtiles = M >> 7;
    const int bm = blockIdx.x % mtiles;
    const int bn = blockIdx.x / mtiles;
    const int row0 = bm << 7;
    const int col0 = bn << 7;
    const int wm = (wave >> 1) << 6;
    const int wn = (wave & 1) << 6;

    floatx4 acc[4][4];
    #pragma unroll
    for (int i = 0; i < 4; ++i)
        #pragma unroll
        for (int j = 0; j < 4; ++j)
            acc[i][j] = (floatx4){0.f, 0.f, 0.f, 0.f};

    const int lr = tid >> 3;
    const int lc = tid & 7;

    for (int k0 = 0; k0 < K; k0 += 64) {
        #pragma unroll
        for (int i = 0; i < 4; ++i) {
            const int r = lr + i * 32;
            const float4 v0 = *reinterpret_cast<const float4*>(
                &A[(size_t)(row0 + r) * K + k0 + lc * 8]);
            const float4 v1 = *reinterpret_cast<const float4*>(
                &A[(size_t)(row0 + r) * K + k0 + lc * 8 + 4]);
            short8 s;
            s[0] = (short)f2bf(v0.x); s[1] = (short)f2bf(v0.y);
            s[2] = (short)f2bf(v0.z); s[3] = (short)f2bf(v0.w);
            s[4] = (short)f2bf(v1.x); s[5] = (short)f2bf(v1.y);
            s[6] = (short)f2bf(v1.z); s[7] = (short)f2bf(v1.w);
            *reinterpret_cast<short8*>(&As[r][lc * 8]) = s;
            *reinterpret_cast<short8*>(&Bs[r][lc * 8]) =
                *reinterpret_cast<const short8*>(
                    &Bt[(size_t)(col0 + r) * K + k0 + lc * 8]);
        }
        __syncthreads();

        #pragma unroll
        for (int kk = 0; kk < 64; kk += 32) {
            short8 af[4], bfr[4];
            #pragma unroll
            for (int i = 0; i < 4; ++i)
                af[i] = *reinterpret_cast<const short8*>(
                    &As[wm + i * 16 + (lane & 15)][kk + (lane >> 4) * 8]);
            #pragma unroll
            for (int j = 0; j < 4; ++j)
                bfr[j] = *reinterpret_cast<const short8*>(
                    &Bs[wn + j * 16 + (lane & 15)][kk + (lane >> 4) * 8]);
            #pragma unroll
            for (int i = 0; i < 4; ++i)
                #pragma unroll
                for (int j = 0; j < 4; ++j)
                    acc[i][j] = __builtin_amdgcn_mfma_f32_16x16x32_bf16(
                        af[i], bfr[j], acc[i][j], 0, 0, 0);
        }
        __syncthreads();
    }

    const int rbase = row0 + wm + (lane >> 4) * 4;
    const int cbase = col0 + wn + (lane & 15);
    #pragma unroll
    for (int j = 0; j < 4; ++j) {
        const float bj = bias[cbase + j * 16];
        #pragma unroll
        for (int i = 0; i < 4; ++i) {
            #pragma unroll
            for (int r = 0; r < 4; ++r) {
                float v = acc[i][j][r] + bj;
                if (relu) v = fmaxf(v, 0.f);
                const size_t idx = (size_t)(rbase + i * 16 + r) * N + cbase + j * 16;
                if (C)   C[idx] = v;
                if (Cbf) Cbf[idx] = f2bf(v);
            }
        }
    }
}

// ---------------------------------------------------------------------------
// MFMA GEMM, A = bf16, staged via global_load_lds width-16 (m97 structure).
// Linear LDS [128][64]; wave-uniform base + lane*16 matches (lr,lc) layout.
// ---------------------------------------------------------------------------
__global__ __launch_bounds__(256) void gemm_lds(
    const unsigned short* __restrict__ A, const unsigned short* __restrict__ Bt,
    const float* __restrict__ bias,
    float* __restrict__ C, unsigned short* __restrict__ Cbf,
    int M, int N, int K, int relu)
{
    __shared__ short As[128 * 64];
    __shared__ short Bs[128 * 64];

    const int tid  = threadIdx.x;
    const int wave = tid >> 6;
    const int lane = tid & 63;
    const int mtiles = M >> 7;
    const int bm = blockIdx.x % mtiles;
    const int bn = blockIdx.x / mtiles;
    const int row0 = bm << 7;
    const int col0 = bn << 7;
    const int wm = (wave >> 1) << 6;
    const int wn = (wave & 1) << 6;

    floatx4 acc[4][4];
    #pragma unroll
    for (int i = 0; i < 4; ++i)
        #pragma unroll
        for (int j = 0; j < 4; ++j)
            acc[i][j] = (floatx4){0.f, 0.f, 0.f, 0.f};

    const int lr = tid >> 3;        // 0..31
    const int lc = tid & 7;
    const unsigned short* Ag = A  + (size_t)(row0 + lr) * K + lc * 8;
    const unsigned short* Bg = Bt + (size_t)(col0 + lr) * K + lc * 8;

    for (int k0 = 0; k0 < K; k0 += 64) {
        #pragma unroll
        for (int i = 0; i < 4; ++i) {
            GLOAD_LDS16(Ag + (size_t)(i * 32) * K + k0, &As[(wave * 8 + i * 32) * 64]);
            GLOAD_LDS16(Bg + (size_t)(i * 32) * K + k0, &Bs[(wave * 8 + i * 32) * 64]);
        }
        __syncthreads();   // drains vmcnt(0) before barrier

        #pragma unroll
        for (int kk = 0; kk < 64; kk += 32) {
            short8 af[4], bfr[4];
            #pragma unroll
            for (int i = 0; i < 4; ++i)
                af[i] = *reinterpret_cast<const short8*>(
                    &As[(wm + i * 16 + (lane & 15)) * 64 + kk + (lane >> 4) * 8]);
            #pragma unroll
            for (int j = 0; j < 4; ++j)
                bfr[j] = *reinterpret_cast<const short8*>(
                    &Bs[(wn + j * 16 + (lane & 15)) * 64 + kk + (lane >> 4) * 8]);
            #pragma unroll
            for (int i = 0; i < 4; ++i)
                #pragma unroll
                for (int j = 0; j < 4; ++j)
                    acc[i][j] = __builtin_amdgcn_mfma_f32_16x16x32_bf16(
                        af[i], bfr[j], acc[i][j], 0, 0, 0);
        }
        __syncthreads();
    }

    const int rbase = row0 + wm + (lane >> 4) * 4;
    const int cbase = col0 + wn + (lane & 15);
    #pragma unroll
    for (int j = 0; j < 4; ++j) {
        const float bj = bias[cbase + j * 16];
        #pragma unroll
        for (int i = 0; i < 4; ++i) {
            #pragma unroll
            for (int r = 0; r < 4; ++r) {
                float v = acc[i][j][r] + bj;
                if (relu) v = fmaxf(v, 0.f);
                const size_t idx = (size_t)(rbase + i * 16 + r) * N + cbase + j * 16;
                if (C)   C[idx] = v;
                if (Cbf) Cbf[idx] = f2bf(v);
            }
        }
    }
}

// ---------------------------------------------------------------------------
// Deformable sampling + fused softmax, 2-phase LDS-staged.
// Block = 256 threads = 64 units (unit = (bq,h)).
// Phase 1 (lane = unit*4 + level): compute softmax + 16 bilinear corners
//   (byte-offset, weight) once per (unit,level); write to LDS meta.
// Phase 2 (lane = unit*4 + chunk c, 8 channels each): 64 x 16B gathers,
//   weights from LDS broadcast, no cross-lane reduce.
// vproj bf16 [B][LV][256]; oa bf16 [MROWS][384] (off 0..255, logits 256..383);
// refs f32 [MROWS][4][2] -> out bf16 [MROWS][256].
// ---------------------------------------------------------------------------
__global__ __launch_bounds__(256) void msda_sample(
    const unsigned short* __restrict__ vproj,
    const unsigned short* __restrict__ oa,
    const float* __restrict__ refs,
    unsigned short* __restrict__ outbf)
{
    // meta[unit][slot]: slot j holds corners 2j,2j+1 as {off0,w0,off1,w1}.
    // Row stride 33*16B = 528B -> unit base bank 4u%32: 2 units/quad = 2-way (free).
    __shared__ uint4 meta[64][33];

    const int tid = threadIdx.x;
    const int ul  = tid >> 2;
    const int u   = (blockIdx.x << 6) + ul;
    const int h   = u & 7;
    const int bq  = u >> 3;

    // ---------------- phase 1: coords (lane = unit, level)
    {
        const int l   = tid & 3;
        const int sl  = 6 - l;
        const int Nl  = 1 << sl;
        const int msk = Nl - 1;
        const int lsi = (l == 0) ? 0 : (l == 1) ? 4096 : (l == 2) ? 5120 : 5376;

        const size_t oabase = (size_t)bq * 384;
        const short8  offv = *reinterpret_cast<const short8*>(oa + oabase + h * 32 + l * 8);
        const ushort4 lgu  = *reinterpret_cast<const ushort4*>(oa + oabase + 256 + h * 16 + l * 4);
        const float2  rr   = *reinterpret_cast<const float2*>(refs + (size_t)bq * 8 + l * 2);

        float lg0 = bf2f(lgu.x), lg1 = bf2f(lgu.y), lg2 = bf2f(lgu.z), lg3 = bf2f(lgu.w);
        float m = fmaxf(fmaxf(lg0, lg1), fmaxf(lg2, lg3));
        m = fmaxf(m, __shfl_xor(m, 1));
        m = fmaxf(m, __shfl_xor(m, 2));
        float e0 = __expf(lg0 - m), e1 = __expf(lg1 - m),
              e2 = __expf(lg2 - m), e3 = __expf(lg3 - m);
        float s = e0 + e1 + e2 + e3;
        s += __shfl_xor(s, 1);
        s += __shfl_xor(s, 2);
        const float inv = 1.f / s;
        const float aw4[4] = {e0 * inv, e1 * inv, e2 * inv, e3 * inv};

        const float Nf = (float)Nl;
        #pragma unroll
        for (int p = 0; p < 4; ++p) {
            const float ox = bf2fs(offv[p * 2 + 0]);
            const float oy = bf2fs(offv[p * 2 + 1]);
            const float aw = aw4[p];
            const float x = fmaf(rr.x, Nf, ox) - 0.5f;
            const float y = fmaf(rr.y, Nf, oy) - 0.5f;
            const float xf = floorf(x), yf = floorf(y);
            const float tx = x - xf, ty = y - yf;
            const int xi = (int)xf, yi = (int)yf;
            const bool x0v = (unsigned)xi < (unsigned)Nl;
            const bool x1v = (unsigned)(xi + 1) < (unsigned)Nl;
            const bool y0v = (unsigned)yi < (unsigned)Nl;
            const bool y1v = (unsigned)(yi + 1) < (unsigned)Nl;
            const float w0x = (1.f - tx) * aw, w1x = tx * aw;
            const int xm0 = xi & msk, xm1 = (xi + 1) & msk;
            const int ym0 = (yi & msk) << sl, ym1 = ((yi + 1) & msk) << sl;
            uint4 m0, m1;
            m0.x = (unsigned)((lsi + (ym0 | xm0)) << 9);   // byte offset: *512
            m0.y = __float_as_uint((x0v & y0v) ? w0x * (1.f - ty) : 0.f);
            m0.z = (unsigned)((lsi + (ym0 | xm1)) << 9);
            m0.w = __float_as_uint((x1v & y0v) ? w1x * (1.f - ty) : 0.f);
            m1.x = (unsigned)((lsi + (ym1 | xm0)) << 9);
            m1.y = __float_as_uint((x0v & y1v) ? w0x * ty : 0.f);
            m1.z = (unsigned)((lsi + (ym1 | xm1)) << 9);
            m1.w = __float_as_uint((x1v & y1v) ? w1x * ty : 0.f);
            meta[ul][l * 8 + p * 2 + 0] = m0;
            meta[ul][l * 8 + p * 2 + 1] = m1;
        }
    }
    __syncthreads();

    // ---------------- phase 2: gather + MAC (lane = unit, 8-ch chunk)
    const int c = tid & 3;
    const int b = bq / LVTOT;
    const unsigned short* vb = vproj + (size_t)b * (LVTOT * 256) + h * 32 + c * 8;

    float acc[8] = {0.f, 0.f, 0.f, 0.f, 0.f, 0.f, 0.f, 0.f};
    #pragma unroll 4
    for (int j = 0; j < 32; ++j) {
        const uint4 mt = meta[ul][j];
        const uint4 g0 = *reinterpret_cast<const uint4*>(
            (const char*)vb + mt.x);
        const uint4 g1 = *reinterpret_cast<const uint4*>(
            (const char*)vb + mt.z);
        const float w0 = __uint_as_float(mt.y);
        const float w1 = __uint_as_float(mt.w);
        #pragma unroll
        for (int d = 0; d < 4; ++d) {
            const unsigned u0 = (&g0.x)[d];
            acc[2 * d]     = fmaf(w0, __uint_as_float(u0 << 16), acc[2 * d]);
            acc[2 * d + 1] = fmaf(w0, __uint_as_float(u0 & 0xffff0000u), acc[2 * d + 1]);
        }
        #pragma unroll
        for (int d = 0; d < 4; ++d) {
            const unsigned u1 = (&g1.x)[d];
            acc[2 * d]     = fmaf(w1, __uint_as_float(u1 << 16), acc[2 * d]);
            acc[2 * d + 1] = fmaf(w1, __uint_as_float(u1 & 0xffff0000u), acc[2 * d + 1]);
        }
    }

    uint4 ov;
    ov.x = (unsigned)f2bf(acc[0]) | ((unsigned)f2bf(acc[1]) << 16);
    ov.y = (unsigned)f2bf(acc[2]) | ((unsigned)f2bf(acc[3]) << 16);
    ov.z = (unsigned)f2bf(acc[4]) | ((unsigned)f2bf(acc[5]) << 16);
    ov.w = (unsigned)f2bf(acc[6]) | ((unsigned)f2bf(acc[7]) << 16);
    *reinterpret_cast<uint4*>(outbf + (size_t)bq * 256 + h * 32 + c * 8) = ov;
}

// ---------------------------------------------------------------------------
// LayerNorm over 256 with fused adds:
//   x = x1 + (x2?:0); y = LN(x)*g + b; out = (res?:0) + y; optional bf16 copy.
// ---------------------------------------------------------------------------
__global__ __launch_bounds__(256) void ln_fused(
    const float* __restrict__ x1, const float* __restrict__ x2,
    const float* __restrict__ res,
    const float* __restrict__ g, const float* __restrict__ bta,
    float* __restrict__ out, unsigned short* __restrict__ outbf)
{
    const int row  = (blockIdx.x << 2) + (threadIdx.x >> 6);
    const int lane = threadIdx.x & 63;
    const size_t base = (size_t)row * 256 + lane * 4;

    float4 v = *reinterpret_cast<const float4*>(&x1[base]);
    if (x2) {
        float4 u = *reinterpret_cast<const float4*>(&x2[base]);
        v.x += u.x; v.y += u.y; v.z += u.z; v.w += u.w;
    }
    float s1 = v.x + v.y + v.z + v.w;
    float s2 = v.x * v.x + v.y * v.y + v.z * v.z + v.w * v.w;
    #pragma unroll
    for (int s = 1; s < 64; s <<= 1) {
        s1 += __shfl_xor(s1, s);
        s2 += __shfl_xor(s2, s);
    }
    const float mu  = s1 * (1.f / 256.f);
    const float var = s2 * (1.f / 256.f) - mu * mu;
    const float rstd = rsqrtf(var + 1e-5f);

    float4 gg = *reinterpret_cast<const float4*>(&g[lane * 4]);
    float4 bb = *reinterpret_cast<const float4*>(&bta[lane * 4]);
    float4 o;
    o.x = (v.x - mu) * rstd * gg.x + bb.x;
    o.y = (v.y - mu) * rstd * gg.y + bb.y;
    o.z = (v.z - mu) * rstd * gg.z + bb.z;
    o.w = (v.w - mu) * rstd * gg.w + bb.w;
    if (res) {
        float4 r = *reinterpret_cast<const float4*>(&res[base]);
        o.x += r.x; o.y += r.y; o.z += r.z; o.w += r.w;
    }
    *reinterpret_cast<float4*>(&out[base]) = o;
    if (outbf) {
        ushort4 ob;
        ob.x = f2bf(o.x); ob.y = f2bf(o.y); ob.z = f2bf(o.z); ob.w = f2bf(o.w);
        reinterpret_cast<ushort4*>(outbf + base - lane * 4)[lane] = ob;
    }
}

// ---------------------------------------------------------------------------
extern "C" void kernel_launch(void* const* d_in, const int* in_sizes, int n_in,
                              void* d_out, int out_size, void* d_ws, size_t ws_size,
                              hipStream_t stream)
{
    const float* query  = (const float*)d_in[0];
    const float* refs   = (const float*)d_in[1];
    const float* value  = (const float*)d_in[2];
    const float* W_off  = (const float*)d_in[5];
    const float* b_off  = (const float*)d_in[6];
    const float* W_attn = (const float*)d_in[7];
    const float* b_attn = (const float*)d_in[8];
    const float* W_val  = (const float*)d_in[9];
    const float* b_val  = (const float*)d_in[10];
    const float* W_out  = (const float*)d_in[11];
    const float* b_out  = (const float*)d_in[12];
    const float* ln1g   = (const float*)d_in[13];
    const float* ln1b   = (const float*)d_in[14];
    const float* ln2g   = (const float*)d_in[15];
    const float* ln2b   = (const float*)d_in[16];
    const float* W_ff1  = (const float*)d_in[17];
    const float* b_ff1  = (const float*)d_in[18];
    const float* W_ff2  = (const float*)d_in[19];
    const float* b_ff2  = (const float*)d_in[20];
    float* out = (float*)d_out;
    float* ws  = (float*)d_ws;

    const size_t R = (size_t)MROWS * 256;   // 5,570,560 floats
    // Workspace (float offsets), lifetime-reused, total ~4.87R ≈ 102 MB:
    unsigned short* wt_base = (unsigned short*)ws;         // 753,664 bf16
    float* bias_oa = ws + 376832;                          // 384 (pad to 512)
    const size_t base0 = 377344;
    unsigned short* oa_bf    = (unsigned short*)(ws + base0);              // 0.75R fl
    unsigned short* vproj_bf = (unsigned short*)(ws + base0 + 3 * R / 4);  // 0.5R fl
    unsigned short* msda_bf  = (unsigned short*)(ws + base0 + 5 * R / 4);  // 0.5R fl
    // f1x pad: [base0+1.75R, base0+2R)
    float* tmp  = ws + base0 + 2 * R;                       // R
    float* qbuf = ws + base0 + 3 * R;                       // R
    unsigned short* qbuf_bf = (unsigned short*)(ws + base0 + 4 * R);       // 0.5R fl
    unsigned short* f1_bf = oa_bf;   // spans 2R floats over dead oa/vproj/msda/pad

    unsigned short* wt_val = wt_base;
    unsigned short* wt_oa  = wt_base + 65536;
    unsigned short* wt_out = wt_base + 163840;
    unsigned short* wt_ff1 = wt_base + 229376;
    unsigned short* wt_ff2 = wt_base + 491520;

    const dim3 blk(256);
    const int mt = MROWS >> 7;   // 170

    // 0: weight prep
    prep_weights<<<dim3(2946), blk, 0, stream>>>(W_val, W_off, W_attn, W_out,
                                                 W_ff1, W_ff2, b_off, b_attn,
                                                 wt_base, bias_oa);
    // 1: value projection (f32 A), bf16 out
    gemm_af32<<<dim3(mt * 2), blk, 0, stream>>>(value, wt_val, b_val,
                                                nullptr, vproj_bf, MROWS, 256, 256, 0);
    // 2: merged offsets+logits projection (f32 A), bf16 out, N=384
    gemm_af32<<<dim3(mt * 3), blk, 0, stream>>>(query, wt_oa, bias_oa,
                                                nullptr, oa_bf, MROWS, 384, 256, 0);
    // 3: sampling (softmax fused; 64 units/block)
    msda_sample<<<dim3(MROWS * 8 / 64), blk, 0, stream>>>(vproj_bf, oa_bf, refs, msda_bf);
    // 4: output projection (gload_lds path)
    gemm_lds<<<dim3(mt * 2), blk, 0, stream>>>(msda_bf, wt_out, b_out,
                                               tmp, nullptr, MROWS, 256, 256, 0);
    // 5: q = value + LN(tmp); bf16 copy for FF1
    ln_fused<<<dim3(MROWS / 4), blk, 0, stream>>>(tmp, nullptr, value, ln1g, ln1b, qbuf, qbuf_bf);
    // 6: f1 = relu(q @ W_ff1), bf16 (oa/vproj/msda regions dead)
    gemm_lds<<<dim3(mt * 8), blk, 0, stream>>>(qbuf_bf, wt_ff1, b_ff1,
                                               nullptr, f1_bf, MROWS, 1024, 256, 1);
    // 7: f2 = f1 @ W_ff2 -> tmp
    gemm_lds<<<dim3(mt * 2), blk, 0, stream>>>(f1_bf, wt_ff2, b_ff2,
                                               tmp, nullptr, MROWS, 256, 1024, 0);
    // 8: out = LN(qbuf + tmp)
    ln_fused<<<dim3(MROWS / 4), blk, 0, stream>>>(qbuf, tmp, nullptr, ln2g, ln2b, out, nullptr);
}